// Round 2
// baseline (1171.162 us; speedup 1.0000x reference)
//
#include <hip/hip_runtime.h>
#include <math.h>

#define Bb 512
#define Ll 71
#define Dd 512
#define Hh 8
#define DH 64
#define MM (Bb*Ll)   // 36352 = 284 * 128

typedef __attribute__((ext_vector_type(8))) short short8;
typedef __attribute__((ext_vector_type(4))) float f32x4;

static __device__ __forceinline__ f32x4 mfma_bf16(short8 a, short8 b, f32x4 c) {
    return __builtin_amdgcn_mfma_f32_16x16x32_bf16(a, b, c, 0, 0, 0);
}

// fp32 -> bf16 with round-to-nearest-even
static __device__ __forceinline__ unsigned short f2bf(float f) {
    union { float f; unsigned u; } v; v.f = f;
    unsigned r = v.u + 0x7FFFu + ((v.u >> 16) & 1u);
    return (unsigned short)(r >> 16);
}

// ---------------------------------------------------------------------------
// ws layout (ushort elements):
//   0        WqT  bf16 [512 n][512 k]
//   262144   WkT  bf16 [512][512]
//   524288   WvT  bf16 [512][512]
//   786432   WoT  bf16 [512][512]
//   1048576  w1T  bf16 [128 n][96 k]   (k >= 71 zeroed)
//   1060864  w2T  bf16 [80 n][128 k]   (n >= 71 rows zeroed)
//   1071104  AT   bf16 [36352][512]    (attention output, big-ws path only)
// ---------------------------------------------------------------------------
#define WS_W1T_OFF 1048576
#define WS_W2T_OFF 1060864
#define WS_AT_OFF  1071104

// Transpose+convert one 64x64 tile of a 512x512 fp32 weight into bf16 [n][k].
__global__ __launch_bounds__(256) void wcvt512(
    const float* __restrict__ W0, const float* __restrict__ W1,
    const float* __restrict__ W2, const float* __restrict__ W3,
    unsigned short* __restrict__ T0, unsigned short* __restrict__ T1,
    unsigned short* __restrict__ T2, unsigned short* __restrict__ T3)
{
    __shared__ unsigned short t[64][72];
    const int m    = blockIdx.x >> 6;
    const int tile = blockIdx.x & 63;
    const float* W = (m == 0) ? W0 : (m == 1) ? W1 : (m == 2) ? W2 : W3;
    unsigned short* T = (m == 0) ? T0 : (m == 1) ? T1 : (m == 2) ? T2 : T3;
    const int tk = (tile >> 3) * 64, tn = (tile & 7) * 64;
    const int ln = threadIdx.x & 63, lr = threadIdx.x >> 6;
#pragma unroll
    for (int r = lr; r < 64; r += 4)
        t[ln][r] = f2bf(W[(size_t)(tk + r) * 512 + tn + ln]);
    __syncthreads();
#pragma unroll
    for (int r = lr; r < 64; r += 4)
        T[(size_t)(tn + r) * 512 + tk + ln] = t[r][ln];
}

// Convert w1 [71][128] -> w1T [128][96] (k>=71 zero) and
//         w2 [128][71] -> w2T [80][128] (n>=71 rows zero).
__global__ __launch_bounds__(256) void sfcvt(
    const float* __restrict__ w1, const float* __restrict__ w2,
    unsigned short* __restrict__ w1T, unsigned short* __restrict__ w2T)
{
    const int tid = threadIdx.x;
    for (int i = tid; i < 128 * 96; i += 256) {
        int n = i / 96, k = i % 96;
        w1T[i] = (k < 71) ? f2bf(w1[(size_t)k * 128 + n]) : (unsigned short)0;
    }
    for (int i = tid; i < 80 * 128; i += 256) {
        int n = i / 128, k = i % 128;
        w2T[i] = (n < 71) ? f2bf(w2[(size_t)k * 71 + n]) : (unsigned short)0;
    }
}

// ---------------------------------------------------------------------------
// Projection accumulate (FAST path): B from pre-transposed bf16 WT [n][k].
// ---------------------------------------------------------------------------
static __device__ __forceinline__ void proj_g(
    const float* __restrict__ Xrows,
    const unsigned short* __restrict__ WT,
    int hs, int wave, int quad, int l16, f32x4 acc[4])
{
    const int arow = wave * 16 + l16;
    const bool ok = (arow < 71);
    const float* ap = Xrows + (size_t)arow * 512 + quad * 8;
    const unsigned short* w0 = WT + (size_t)(hs + l16) * 512 + quad * 8;
#pragma unroll 4
    for (int kk = 0; kk < 16; ++kk) {
        short8 a;
        if (ok) {
            const f32x4 p0 = *(const f32x4*)(ap + (size_t)kk * 32);
            const f32x4 p1 = *(const f32x4*)(ap + (size_t)kk * 32 + 4);
#pragma unroll
            for (int j = 0; j < 4; j++) {
                a[j]     = (short)f2bf(p0[j]);
                a[4 + j] = (short)f2bf(p1[j]);
            }
        } else {
            a = (short8){0,0,0,0,0,0,0,0};
        }
#pragma unroll
        for (int t = 0; t < 4; t++) {
            short8 bw = *(const short8*)(w0 + (size_t)t * (16 * 512) + kk * 32);
            acc[t] = mfma_bf16(a, bw, acc[t]);
        }
    }
}

// Projection accumulate (LEGACY path): gather fp32 W [k][n] and convert.
static __device__ __forceinline__ void proj_g_legacy(
    const float* __restrict__ Xrows,
    const float* __restrict__ W,
    int hs, int wave, int quad, int l16, f32x4 acc[4])
{
    const int arow = wave * 16 + l16;
    const bool ok = (arow < 71);
    const float* ap = Xrows + (size_t)arow * 512 + quad * 8;
    const int nb = hs + l16;
#pragma unroll 2
    for (int kk = 0; kk < 16; ++kk) {
        short8 a;
        if (ok) {
            const float* p = ap + (size_t)kk * 32;
#pragma unroll
            for (int j = 0; j < 8; j++) a[j] = (short)f2bf(p[j]);
        } else {
            a = (short8){0,0,0,0,0,0,0,0};
        }
        const int k0 = kk * 32 + quad * 8;
#pragma unroll
        for (int t = 0; t < 4; t++) {
            const float* wp = W + (size_t)k0 * 512 + nb + t * 16;
            short8 bw;
#pragma unroll
            for (int j = 0; j < 8; j++) bw[j] = (short)f2bf(wp[(size_t)j * 512]);
            acc[t] = mfma_bf16(a, bw, acc[t]);
        }
    }
}

// ---------------------------------------------------------------------------
// Kernel 1: fused QKV-projection + attention per (b,h). 320 threads = 5 waves.
// MODE 0: bf16 weights, fp32 out to X2.   MODE 1: bf16 weights, bf16 out to AT.
// MODE 2: legacy (fp32 weight gather, fp32 out to X2, zero ws).
// ---------------------------------------------------------------------------
template<int MODE>
__global__ __launch_bounds__(320) void attn_fused(
    const float* __restrict__ query,
    const float* __restrict__ key_,
    const float* __restrict__ value,
    const void* __restrict__ Wq_, const float* __restrict__ bq,
    const void* __restrict__ Wk_, const float* __restrict__ bk,
    const void* __restrict__ Wv_, const float* __restrict__ bv,
    const void* __restrict__ w1_,            // bf16 [128][96] or fp32 [71][128]
    const float* __restrict__ b1,            // [128]
    const void* __restrict__ w2_,            // bf16 [80][128] or fp32 [128][71]
    const float* __restrict__ b2,            // [71]
    float* __restrict__ X2,                  // [36352][512] fp32 (MODE 0/2)
    unsigned short* __restrict__ AT)         // [36352][512] bf16 (MODE 1)
{
    __shared__ __align__(16) unsigned short smem[26496];
    unsigned short* Qs  = smem;              // [80][72] bf16
    unsigned short* Ks  = smem + 5760;       // [80][72] bf16
    unsigned short* H1s = smem;              // [80][136] overlays Qs+Ks
    unsigned short* VTs = smem + 11520;      // [64][104]  V^T, k-contig
    unsigned short* Sb  = smem + 18176;      // [80][104]

    const int tid = threadIdx.x;
    const int wave = tid >> 6, lane = tid & 63;
    const int quad = lane >> 4, l16 = lane & 15;
    // XCD-aware remap: 8 head-blocks of one batch land on the same XCD
    // (XCD = blockIdx % 8 heuristic) within a 64-block dispatch window.
    const int x = blockIdx.x;
    const int b = ((x >> 6) << 3) | (x & 7);
    const int h = (x >> 3) & 7;
    const int hs = h * 64;
    const float* Xq = query + (size_t)(b * 71) * 512;
    const float* Xk = key_  + (size_t)(b * 71) * 512;
    const float* Xv = value + (size_t)(b * 71) * 512;

    // zero pads (MFMA 0*junk != 0 unless pads are real zeros)
    for (int i = tid; i < 1280; i += 320) {           // Sb cols [80,96)
        int r = i >> 4, c = 80 + (i & 15);
        Sb[r * 104 + c] = 0;
    }
    for (int i = tid; i < 1024; i += 320) {           // VTs k-cols [80,96)
        int n = i >> 4, c = 80 + (i & 15);
        VTs[n * 104 + c] = 0;
    }

    // ---- Q projection -> Qs[80][72]
    {
        f32x4 acc[4];
#pragma unroll
        for (int t = 0; t < 4; t++) acc[t] = (f32x4){0.f, 0.f, 0.f, 0.f};
        if (MODE == 2) proj_g_legacy(Xq, (const float*)Wq_, hs, wave, quad, l16, acc);
        else           proj_g(Xq, (const unsigned short*)Wq_, hs, wave, quad, l16, acc);
#pragma unroll
        for (int t = 0; t < 4; t++) {
            int col = t * 16 + l16;
            float bb = bq[hs + col];
#pragma unroll
            for (int r = 0; r < 4; r++) {
                int row = wave * 16 + quad * 4 + r;
                Qs[row * 72 + col] = f2bf(acc[t][r] + bb);
            }
        }
    }
    // ---- K projection -> Ks[80][72]
    {
        f32x4 acc[4];
#pragma unroll
        for (int t = 0; t < 4; t++) acc[t] = (f32x4){0.f, 0.f, 0.f, 0.f};
        if (MODE == 2) proj_g_legacy(Xk, (const float*)Wk_, hs, wave, quad, l16, acc);
        else           proj_g(Xk, (const unsigned short*)Wk_, hs, wave, quad, l16, acc);
#pragma unroll
        for (int t = 0; t < 4; t++) {
            int col = t * 16 + l16;
            float bb = bk[hs + col];
#pragma unroll
            for (int r = 0; r < 4; r++) {
                int row = wave * 16 + quad * 4 + r;
                Ks[row * 72 + col] = f2bf(acc[t][r] + bb);
            }
        }
    }
    // ---- V projection -> VTs[64][104] transposed; k-rows >=71 stored as 0
    {
        f32x4 acc[4];
#pragma unroll
        for (int t = 0; t < 4; t++) acc[t] = (f32x4){0.f, 0.f, 0.f, 0.f};
        if (MODE == 2) proj_g_legacy(Xv, (const float*)Wv_, hs, wave, quad, l16, acc);
        else           proj_g(Xv, (const unsigned short*)Wv_, hs, wave, quad, l16, acc);
#pragma unroll
        for (int t = 0; t < 4; t++) {
            int col = t * 16 + l16;
            float bb = bv[hs + col];
#pragma unroll
            for (int r = 0; r < 4; r++) {
                int row = wave * 16 + quad * 4 + r;
                float v = (row < 71) ? (acc[t][r] + bb) : 0.f;
                VTs[col * 104 + row] = f2bf(v);
            }
        }
    }
    __syncthreads();

    // ---- phase 1: scores = Q K^T / 8   (C-layout regs kept live)
    f32x4 sacc[5];
#pragma unroll
    for (int t = 0; t < 5; t++) sacc[t] = (f32x4){0.f, 0.f, 0.f, 0.f};
#pragma unroll
    for (int kk = 0; kk < 2; kk++) {
        short8 aq = *(const short8*)&Qs[(wave * 16 + l16) * 72 + kk * 32 + quad * 8];
#pragma unroll
        for (int t = 0; t < 5; t++) {
            short8 bk_ = *(const short8*)&Ks[(t * 16 + l16) * 72 + kk * 32 + quad * 8];
            sacc[t] = mfma_bf16(aq, bk_, sacc[t]);
        }
    }
#pragma unroll
    for (int t = 0; t < 5; t++) {
#pragma unroll
        for (int r = 0; r < 4; r++) {
            sacc[t][r] *= 0.125f;
            int row = wave * 16 + quad * 4 + r, col = t * 16 + l16;
            Sb[row * 104 + col] = f2bf(sacc[t][r]);
        }
    }
    __syncthreads();

    // ---- phase 2: H1 = gelu(S @ W1 + b1)
    f32x4 hacc[8];
#pragma unroll
    for (int t = 0; t < 8; t++) hacc[t] = (f32x4){0.f, 0.f, 0.f, 0.f};
#pragma unroll
    for (int kk = 0; kk < 3; kk++) {
        short8 a = *(const short8*)&Sb[(wave * 16 + l16) * 104 + kk * 32 + quad * 8];
        const int k0 = kk * 32 + quad * 8;
#pragma unroll
        for (int t = 0; t < 8; t++) {
            short8 bw;
            if (MODE == 2) {
                const float* wp = (const float*)w1_ + (size_t)k0 * 128 + t * 16 + l16;
#pragma unroll
                for (int j = 0; j < 8; j++)
                    bw[j] = (k0 + j < 71) ? (short)f2bf(wp[(size_t)j * 128]) : (short)0;
            } else {
                bw = *(const short8*)&((const unsigned short*)w1_)[(size_t)(t * 16 + l16) * 96 + k0];
            }
            hacc[t] = mfma_bf16(a, bw, hacc[t]);
        }
    }
#pragma unroll
    for (int t = 0; t < 8; t++) {
        int col = t * 16 + l16;
        float bvf = b1[col];
#pragma unroll
        for (int r = 0; r < 4; r++) {
            float z = hacc[t][r] + bvf;
            float g = 0.5f * z * (1.0f + erff(z * 0.70710678118654752f));
            int row = wave * 16 + quad * 4 + r;
            H1s[row * 136 + col] = f2bf(g);
        }
    }
    __syncthreads();

    // ---- phase 3: G = H1 @ W2
    f32x4 gacc[5];
#pragma unroll
    for (int t = 0; t < 5; t++) gacc[t] = (f32x4){0.f, 0.f, 0.f, 0.f};
#pragma unroll
    for (int kk = 0; kk < 4; kk++) {
        short8 a = *(const short8*)&H1s[(wave * 16 + l16) * 136 + kk * 32 + quad * 8];
        const int k0 = kk * 32 + quad * 8;
#pragma unroll
        for (int t = 0; t < 5; t++) {
            short8 bw;
            if (MODE == 2) {
                const int n = t * 16 + l16;
                const float* wp = (const float*)w2_ + (size_t)k0 * 71 + n;
#pragma unroll
                for (int j = 0; j < 8; j++)
                    bw[j] = (n < 71) ? (short)f2bf(wp[(size_t)j * 71]) : (short)0;
            } else {
                bw = *(const short8*)&((const unsigned short*)w2_)[(size_t)(t * 16 + l16) * 128 + k0];
            }
            gacc[t] = mfma_bf16(a, bw, gacc[t]);
        }
    }
#pragma unroll
    for (int t = 0; t < 5; t++) {
        int col = t * 16 + l16;
        float b2v = (col < 71) ? b2[col] : 0.f;
#pragma unroll
        for (int r = 0; r < 4; r++)
            sacc[t][r] = sacc[t][r] + gacc[t][r] + b2v;
    }

    // ---- phase 4: softmax over cols 0..70 (row spread over 16 lanes x 5 regs)
    bool valid4 = (l16 < 7);
#pragma unroll
    for (int r = 0; r < 4; r++) {
        float mx = -1e30f;
#pragma unroll
        for (int t = 0; t < 5; t++) {
            float v = sacc[t][r];
            if (t == 4 && !valid4) v = -1e30f;
            mx = fmaxf(mx, v);
        }
#pragma unroll
        for (int off = 1; off < 16; off <<= 1) mx = fmaxf(mx, __shfl_xor(mx, off, 16));
        float sum = 0.f;
#pragma unroll
        for (int t = 0; t < 5; t++) {
            float e = (t == 4 && !valid4) ? 0.f : __expf(sacc[t][r] - mx);
            sacc[t][r] = e;
            sum += e;
        }
#pragma unroll
        for (int off = 1; off < 16; off <<= 1) sum += __shfl_xor(sum, off, 16);
        float inv = 1.0f / sum;
#pragma unroll
        for (int t = 0; t < 5; t++) sacc[t][r] *= inv;
    }
#pragma unroll
    for (int t = 0; t < 5; t++) {
#pragma unroll
        for (int r = 0; r < 4; r++) {
            int row = wave * 16 + quad * 4 + r, col = t * 16 + l16;
            Sb[row * 104 + col] = f2bf(sacc[t][r]);   // P; cols 71..95 exact 0
        }
    }
    __syncthreads();

    // ---- phase 5: O = P @ V ; store to AT (bf16) or X2 (fp32)
    f32x4 oacc[4];
#pragma unroll
    for (int t = 0; t < 4; t++) oacc[t] = (f32x4){0.f, 0.f, 0.f, 0.f};
#pragma unroll
    for (int kk = 0; kk < 3; kk++) {
        short8 a = *(const short8*)&Sb[(wave * 16 + l16) * 104 + kk * 32 + quad * 8];
#pragma unroll
        for (int t = 0; t < 4; t++) {
            short8 bvv = *(const short8*)&VTs[(t * 16 + l16) * 104 + kk * 32 + quad * 8];
            oacc[t] = mfma_bf16(a, bvv, oacc[t]);
        }
    }
#pragma unroll
    for (int r = 0; r < 4; r++) {
        int l = wave * 16 + quad * 4 + r;
        if (l < 71) {
#pragma unroll
            for (int t = 0; t < 4; t++) {
                int col = hs + t * 16 + l16;
                if (MODE == 1)
                    AT[(size_t)(b * 71 + l) * 512 + col] = f2bf(oacc[t][r]);
                else
                    X2[(size_t)(b * 71 + l) * 512 + col] = oacc[t][r];
            }
        }
    }
}

// ---------------------------------------------------------------------------
// Kernel 2a: output projection, bf16 A from ws, bf16 B from WoT. Pure MFMA.
// ---------------------------------------------------------------------------
__global__ __launch_bounds__(512, 2) void gemm_o_bf16(
    const unsigned short* __restrict__ WoT,  // [512 n][512 k] bf16
    const float* __restrict__ bo,            // [512] fp32
    const unsigned short* __restrict__ AT,   // [36352][512] bf16
    float* __restrict__ Y)                   // [36352][512] fp32 out
{
    const int tid  = threadIdx.x;
    const int wave = tid >> 6, lane = tid & 63;
    const int quad = lane >> 4, l16 = lane & 15;
    const int m0 = blockIdx.x * 128;
    const int wm = (wave >> 2) * 64, wn = (wave & 3) * 128;

    f32x4 acc[4][8];
#pragma unroll
    for (int i = 0; i < 4; i++)
#pragma unroll
        for (int j = 0; j < 8; j++) acc[i][j] = (f32x4){0.f, 0.f, 0.f, 0.f};

    for (int kk = 0; kk < 16; ++kk) {
        const int k0 = kk * 32 + quad * 8;
        short8 af[4];
#pragma unroll
        for (int i = 0; i < 4; i++)
            af[i] = *(const short8*)&AT[(size_t)(m0 + wm + i * 16 + l16) * 512 + k0];
        short8 bfr[8];
#pragma unroll
        for (int j = 0; j < 8; j++)
            bfr[j] = *(const short8*)&WoT[(size_t)(wn + j * 16 + l16) * 512 + k0];
#pragma unroll
        for (int i = 0; i < 4; i++)
#pragma unroll
            for (int j = 0; j < 8; j++)
                acc[i][j] = mfma_bf16(af[i], bfr[j], acc[i][j]);
    }

#pragma unroll
    for (int j = 0; j < 8; j++) {
        int gcol = wn + j * 16 + l16;
        float bvf = bo[gcol];
#pragma unroll
        for (int i = 0; i < 4; i++) {
#pragma unroll
            for (int r = 0; r < 4; r++) {
                int grow = m0 + wm + i * 16 + quad * 4 + r;
                Y[(size_t)grow * 512 + gcol] = acc[i][j][r] + bvf;
            }
        }
    }
}

// ---------------------------------------------------------------------------
// Kernel 2b: in-place on fp32 Y. WMODE 0: bf16 WoT. WMODE 1: fp32 Wo gather.
// ---------------------------------------------------------------------------
template<int WMODE>
__global__ __launch_bounds__(512, 2) void gemm_o_inplace(
    const void* __restrict__ Wo_,
    const float* __restrict__ bo,
    float* __restrict__ Y)                   // [36352][512] fp32, in/out
{
    const int tid  = threadIdx.x;
    const int wave = tid >> 6, lane = tid & 63;
    const int quad = lane >> 4, l16 = lane & 15;
    const int m0 = blockIdx.x * 128;
    const int wm = (wave >> 2) * 64, wn = (wave & 3) * 128;

    f32x4 acc[4][8];
#pragma unroll
    for (int i = 0; i < 4; i++)
#pragma unroll
        for (int j = 0; j < 8; j++) acc[i][j] = (f32x4){0.f, 0.f, 0.f, 0.f};

    for (int kk = 0; kk < 16; ++kk) {
        const int k0 = kk * 32 + quad * 8;
        short8 af[4];
#pragma unroll
        for (int i = 0; i < 4; i++) {
            const float* p = Y + (size_t)(m0 + wm + i * 16 + l16) * 512 + k0;
            short8 a;
#pragma unroll
            for (int j = 0; j < 8; j++) a[j] = (short)f2bf(p[j]);
            af[i] = a;
        }
        short8 bfr[8];
#pragma unroll
        for (int j = 0; j < 8; j++) {
            if (WMODE == 1) {
                const float* wp = (const float*)Wo_ + (size_t)k0 * 512 + wn + j * 16 + l16;
                short8 bw;
#pragma unroll
                for (int e = 0; e < 8; e++) bw[e] = (short)f2bf(wp[(size_t)e * 512]);
                bfr[j] = bw;
            } else {
                bfr[j] = *(const short8*)&((const unsigned short*)Wo_)[(size_t)(wn + j * 16 + l16) * 512 + k0];
            }
        }
#pragma unroll
        for (int i = 0; i < 4; i++)
#pragma unroll
            for (int j = 0; j < 8; j++)
                acc[i][j] = mfma_bf16(af[i], bfr[j], acc[i][j]);
    }

    __syncthreads();   // all A-reads in this block complete before any write

#pragma unroll
    for (int j = 0; j < 8; j++) {
        int gcol = wn + j * 16 + l16;
        float bvf = bo[gcol];
#pragma unroll
        for (int i = 0; i < 4; i++) {
#pragma unroll
            for (int r = 0; r < 4; r++) {
                int grow = m0 + wm + i * 16 + quad * 4 + r;
                Y[(size_t)grow * 512 + gcol] = acc[i][j][r] + bvf;
            }
        }
    }
}

extern "C" void kernel_launch(void* const* d_in, const int* in_sizes, int n_in,
                              void* d_out, int out_size, void* d_ws, size_t ws_size,
                              hipStream_t stream) {
    (void)in_sizes; (void)n_in; (void)out_size;
    const float* query = (const float*)d_in[0];
    const float* key_  = (const float*)d_in[1];
    const float* value = (const float*)d_in[2];
    const float* Wq = (const float*)d_in[3];
    const float* bq = (const float*)d_in[4];
    const float* Wk = (const float*)d_in[5];
    const float* bk = (const float*)d_in[6];
    const float* Wv = (const float*)d_in[7];
    const float* bv = (const float*)d_in[8];
    const float* Wo = (const float*)d_in[9];
    const float* bo = (const float*)d_in[10];
    const float* w1 = (const float*)d_in[11];
    const float* b1 = (const float*)d_in[12];
    const float* w2 = (const float*)d_in[13];
    const float* b2 = (const float*)d_in[14];

    unsigned short* wsT = (unsigned short*)d_ws;
    unsigned short* WqT = wsT;
    unsigned short* WkT = wsT + 262144;
    unsigned short* WvT = wsT + 524288;
    unsigned short* WoT = wsT + 786432;
    unsigned short* w1T = wsT + WS_W1T_OFF;
    unsigned short* w2T = wsT + WS_W2T_OFF;
    unsigned short* AT  = wsT + WS_AT_OFF;
    const size_t NEED_W   = (size_t)WS_AT_OFF * 2;                        // ~2.1 MB
    const size_t NEED_BIG = NEED_W + (size_t)MM * 512 * 2;                // ~39.4 MB

    float* X2 = (float*)d_out;

    if (d_ws == nullptr || ws_size < NEED_W) {
        // LEGACY path (verified baseline): zero workspace bytes used.
        attn_fused<2><<<4096, 320, 0, stream>>>(query, key_, value,
                                                Wq, bq, Wk, bk, Wv, bv,
                                                w1, b1, w2, b2, X2, nullptr);
        gemm_o_inplace<1><<<284, 512, 0, stream>>>(Wo, bo, X2);
        return;
    }

    wcvt512<<<256, 256, 0, stream>>>(Wq, Wk, Wv, Wo, WqT, WkT, WvT, WoT);
    sfcvt<<<1, 256, 0, stream>>>(w1, w2, w1T, w2T);

    if (ws_size >= NEED_BIG) {
        attn_fused<1><<<4096, 320, 0, stream>>>(query, key_, value,
                                                WqT, bq, WkT, bk, WvT, bv,
                                                w1T, b1, w2T, b2, nullptr, AT);
        gemm_o_bf16<<<284, 512, 0, stream>>>(WoT, bo, AT, X2);
    } else {
        attn_fused<0><<<4096, 320, 0, stream>>>(query, key_, value,
                                                WqT, bq, WkT, bk, WvT, bv,
                                                w1T, b1, w2T, b2, X2, nullptr);
        gemm_o_inplace<0><<<284, 512, 0, stream>>>(WoT, bo, X2);
    }
}

// Round 4
// 1087.806 us; speedup vs baseline: 1.0766x; 1.0766x over previous
//
#include <hip/hip_runtime.h>
#include <math.h>

#define Bb 512
#define Ll 71
#define Dd 512
#define Hh 8
#define DH 64
#define MM (Bb*Ll)   // 36352 = 284 * 128

typedef __attribute__((ext_vector_type(8))) short short8;
typedef __attribute__((ext_vector_type(4))) float f32x4;

static __device__ __forceinline__ f32x4 mfma_bf16(short8 a, short8 b, f32x4 c) {
    return __builtin_amdgcn_mfma_f32_16x16x32_bf16(a, b, c, 0, 0, 0);
}

// fp32 -> bf16 with round-to-nearest-even
static __device__ __forceinline__ unsigned short f2bf(float f) {
    union { float f; unsigned u; } v; v.f = f;
    unsigned r = v.u + 0x7FFFu + ((v.u >> 16) & 1u);
    return (unsigned short)(r >> 16);
}

// ---------------------------------------------------------------------------
// ws layout (ushort elements):
//   0        WqT  bf16 [512 n][512 k]
//   262144   WkT  bf16 [512][512]
//   524288   WvT  bf16 [512][512]
//   786432   WoT  bf16 [512][512]
//   1048576  w1T  bf16 [128 n][96 k]   (k >= 71 zeroed)
//   1060864  w2T  bf16 [80 n][128 k]   (n >= 71 rows zeroed)
//   1071104  AT   bf16 [36352][512]    (attention output)
//   19683328 Xqb  bf16 [36352][512]    (query, pre-converted)
//   38295552 Xkb  bf16 [36352][512]
//   56907776 Xvb  bf16 [36352][512]
// ---------------------------------------------------------------------------
#define WS_W1T_OFF 1048576
#define WS_W2T_OFF 1060864
#define WS_AT_OFF  1071104
#define WS_XQ_OFF  19683328
#define WS_XK_OFF  38295552
#define WS_XV_OFF  56907776

// Transpose+convert one 64x64 tile of a 512x512 fp32 weight into bf16 [n][k].
__global__ __launch_bounds__(256) void wcvt512(
    const float* __restrict__ W0, const float* __restrict__ W1,
    const float* __restrict__ W2, const float* __restrict__ W3,
    unsigned short* __restrict__ T0, unsigned short* __restrict__ T1,
    unsigned short* __restrict__ T2, unsigned short* __restrict__ T3)
{
    __shared__ unsigned short t[64][72];
    const int m    = blockIdx.x >> 6;
    const int tile = blockIdx.x & 63;
    const float* W = (m == 0) ? W0 : (m == 1) ? W1 : (m == 2) ? W2 : W3;
    unsigned short* T = (m == 0) ? T0 : (m == 1) ? T1 : (m == 2) ? T2 : T3;
    const int tk = (tile >> 3) * 64, tn = (tile & 7) * 64;
    const int ln = threadIdx.x & 63, lr = threadIdx.x >> 6;
#pragma unroll
    for (int r = lr; r < 64; r += 4)
        t[ln][r] = f2bf(W[(size_t)(tk + r) * 512 + tn + ln]);
    __syncthreads();
#pragma unroll
    for (int r = lr; r < 64; r += 4)
        T[(size_t)(tn + r) * 512 + tk + ln] = t[r][ln];
}

// Convert w1 [71][128] -> w1T [128][96] (k>=71 zero) and
//         w2 [128][71] -> w2T [80][128] (n>=71 rows zero).
__global__ __launch_bounds__(256) void sfcvt(
    const float* __restrict__ w1, const float* __restrict__ w2,
    unsigned short* __restrict__ w1T, unsigned short* __restrict__ w2T)
{
    const int tid = threadIdx.x;
    for (int i = tid; i < 128 * 96; i += 256) {
        int n = i / 96, k = i % 96;
        w1T[i] = (k < 71) ? f2bf(w1[(size_t)k * 128 + n]) : (unsigned short)0;
    }
    for (int i = tid; i < 80 * 128; i += 256) {
        int n = i / 128, k = i % 128;
        w2T[i] = (n < 71) ? f2bf(w2[(size_t)k * 71 + n]) : (unsigned short)0;
    }
}

// Elementwise fp32 -> bf16 for the three X inputs. 16B stores, grid-stride.
__global__ __launch_bounds__(256) void xcvt(
    const float* __restrict__ A, const float* __restrict__ B_,
    const float* __restrict__ C,
    unsigned short* __restrict__ Ab, unsigned short* __restrict__ Bbf,
    unsigned short* __restrict__ Cb)
{
    const size_t N = (size_t)MM * 512;
    const size_t stride = (size_t)gridDim.x * 256 * 8;
    for (size_t i = ((size_t)blockIdx.x * 256 + threadIdx.x) * 8; i < N; i += stride) {
        f32x4 a0 = *(const f32x4*)(A + i),  a1 = *(const f32x4*)(A + i + 4);
        f32x4 b0 = *(const f32x4*)(B_ + i), b1 = *(const f32x4*)(B_ + i + 4);
        f32x4 c0 = *(const f32x4*)(C + i),  c1 = *(const f32x4*)(C + i + 4);
        short8 oa, ob, oc;
#pragma unroll
        for (int j = 0; j < 4; j++) {
            oa[j] = (short)f2bf(a0[j]); oa[4 + j] = (short)f2bf(a1[j]);
            ob[j] = (short)f2bf(b0[j]); ob[4 + j] = (short)f2bf(b1[j]);
            oc[j] = (short)f2bf(c0[j]); oc[4 + j] = (short)f2bf(c1[j]);
        }
        *(short8*)(Ab + i)  = oa;
        *(short8*)(Bbf + i) = ob;
        *(short8*)(Cb + i)  = oc;
    }
}

// ---------------------------------------------------------------------------
// Projection accumulate (bf16-A FAST path): A and B both direct short8 loads.
// Full unroll -> compiler hoists loads as deep as registers allow.
// ---------------------------------------------------------------------------
static __device__ __forceinline__ void proj_bb(
    const unsigned short* __restrict__ Xb,   // this batch's rows [71][512] bf16
    const unsigned short* __restrict__ WT,
    int hs, int wave, int quad, int l16, f32x4 acc[4])
{
    const int arow = wave * 16 + l16;
    const bool ok = (arow < 71);
    const unsigned short* ap = Xb + (size_t)arow * 512 + quad * 8;
    const unsigned short* w0 = WT + (size_t)(hs + l16) * 512 + quad * 8;
#pragma unroll
    for (int kk = 0; kk < 16; ++kk) {
        short8 a = ok ? *(const short8*)(ap + kk * 32)
                      : (short8){0,0,0,0,0,0,0,0};
#pragma unroll
        for (int t = 0; t < 4; t++) {
            short8 bw = *(const short8*)(w0 + (size_t)t * (16 * 512) + kk * 32);
            acc[t] = mfma_bf16(a, bw, acc[t]);
        }
    }
}

// Projection accumulate (fp32-A path): B from pre-transposed bf16 WT [n][k].
static __device__ __forceinline__ void proj_g(
    const float* __restrict__ Xrows,
    const unsigned short* __restrict__ WT,
    int hs, int wave, int quad, int l16, f32x4 acc[4])
{
    const int arow = wave * 16 + l16;
    const bool ok = (arow < 71);
    const float* ap = Xrows + (size_t)arow * 512 + quad * 8;
    const unsigned short* w0 = WT + (size_t)(hs + l16) * 512 + quad * 8;
#pragma unroll 4
    for (int kk = 0; kk < 16; ++kk) {
        short8 a;
        if (ok) {
            const f32x4 p0 = *(const f32x4*)(ap + (size_t)kk * 32);
            const f32x4 p1 = *(const f32x4*)(ap + (size_t)kk * 32 + 4);
#pragma unroll
            for (int j = 0; j < 4; j++) {
                a[j]     = (short)f2bf(p0[j]);
                a[4 + j] = (short)f2bf(p1[j]);
            }
        } else {
            a = (short8){0,0,0,0,0,0,0,0};
        }
#pragma unroll
        for (int t = 0; t < 4; t++) {
            short8 bw = *(const short8*)(w0 + (size_t)t * (16 * 512) + kk * 32);
            acc[t] = mfma_bf16(a, bw, acc[t]);
        }
    }
}

// Projection accumulate (LEGACY path): gather fp32 W [k][n] and convert.
static __device__ __forceinline__ void proj_g_legacy(
    const float* __restrict__ Xrows,
    const float* __restrict__ W,
    int hs, int wave, int quad, int l16, f32x4 acc[4])
{
    const int arow = wave * 16 + l16;
    const bool ok = (arow < 71);
    const float* ap = Xrows + (size_t)arow * 512 + quad * 8;
    const int nb = hs + l16;
#pragma unroll 2
    for (int kk = 0; kk < 16; ++kk) {
        short8 a;
        if (ok) {
            const float* p = ap + (size_t)kk * 32;
#pragma unroll
            for (int j = 0; j < 8; j++) a[j] = (short)f2bf(p[j]);
        } else {
            a = (short8){0,0,0,0,0,0,0,0};
        }
        const int k0 = kk * 32 + quad * 8;
#pragma unroll
        for (int t = 0; t < 4; t++) {
            const float* wp = W + (size_t)k0 * 512 + nb + t * 16;
            short8 bw;
#pragma unroll
            for (int j = 0; j < 8; j++) bw[j] = (short)f2bf(wp[(size_t)j * 512]);
            acc[t] = mfma_bf16(a, bw, acc[t]);
        }
    }
}

// ---------------------------------------------------------------------------
// Kernel 1: fused QKV-projection + attention per (b,h). 320 threads = 5 waves.
// MODE 0: bf16 W, fp32 X, fp32 out.  MODE 1: bf16 W, fp32 X, bf16 out.
// MODE 2: legacy fp32 everything.    MODE 3: bf16 W, bf16 X, bf16 out.
// ---------------------------------------------------------------------------
template<int MODE>
__global__ __launch_bounds__(320) void attn_fused(
    const float* __restrict__ query,
    const float* __restrict__ key_,
    const float* __restrict__ value,
    const unsigned short* __restrict__ Xqb,
    const unsigned short* __restrict__ Xkb,
    const unsigned short* __restrict__ Xvb,
    const void* __restrict__ Wq_, const float* __restrict__ bq,
    const void* __restrict__ Wk_, const float* __restrict__ bk,
    const void* __restrict__ Wv_, const float* __restrict__ bv,
    const void* __restrict__ w1_,            // bf16 [128][96] or fp32 [71][128]
    const float* __restrict__ b1,            // [128]
    const void* __restrict__ w2_,            // bf16 [80][128] or fp32 [128][71]
    const float* __restrict__ b2,            // [71]
    float* __restrict__ X2,                  // [36352][512] fp32 (MODE 0/2)
    unsigned short* __restrict__ AT)         // [36352][512] bf16 (MODE 1/3)
{
    __shared__ __align__(16) unsigned short smem[26496];
    unsigned short* Qs  = smem;              // [80][72] bf16
    unsigned short* Ks  = smem + 5760;       // [80][72] bf16
    unsigned short* H1s = smem;              // [80][136] overlays Qs+Ks
    unsigned short* VTs = smem + 11520;      // [64][104]  V^T, k-contig
    unsigned short* Sb  = smem + 18176;      // [80][104]

    const int tid = threadIdx.x;
    const int wave = tid >> 6, lane = tid & 63;
    const int quad = lane >> 4, l16 = lane & 15;
    // XCD-aware remap: 8 head-blocks of one batch land on the same XCD.
    const int x = blockIdx.x;
    const int b = ((x >> 6) << 3) | (x & 7);
    const int h = (x >> 3) & 7;
    const int hs = h * 64;
    const float* Xq = query + (size_t)(b * 71) * 512;
    const float* Xk = key_  + (size_t)(b * 71) * 512;
    const float* Xv = value + (size_t)(b * 71) * 512;
    const unsigned short* Xqr = (MODE == 3) ? Xqb + (size_t)(b * 71) * 512 : nullptr;
    const unsigned short* Xkr = (MODE == 3) ? Xkb + (size_t)(b * 71) * 512 : nullptr;
    const unsigned short* Xvr = (MODE == 3) ? Xvb + (size_t)(b * 71) * 512 : nullptr;

    // zero pads (MFMA 0*junk != 0 unless pads are real zeros)
    for (int i = tid; i < 1280; i += 320) {           // Sb cols [80,96)
        int r = i >> 4, c = 80 + (i & 15);
        Sb[r * 104 + c] = 0;
    }
    for (int i = tid; i < 1024; i += 320) {           // VTs k-cols [80,96)
        int n = i >> 4, c = 80 + (i & 15);
        VTs[n * 104 + c] = 0;
    }

    // ---- Q projection -> Qs[80][72]
    {
        f32x4 acc[4];
#pragma unroll
        for (int t = 0; t < 4; t++) acc[t] = (f32x4){0.f, 0.f, 0.f, 0.f};
        if (MODE == 2)      proj_g_legacy(Xq, (const float*)Wq_, hs, wave, quad, l16, acc);
        else if (MODE == 3) proj_bb(Xqr, (const unsigned short*)Wq_, hs, wave, quad, l16, acc);
        else                proj_g(Xq, (const unsigned short*)Wq_, hs, wave, quad, l16, acc);
#pragma unroll
        for (int t = 0; t < 4; t++) {
            int col = t * 16 + l16;
            float bb = bq[hs + col];
#pragma unroll
            for (int r = 0; r < 4; r++) {
                int row = wave * 16 + quad * 4 + r;
                Qs[row * 72 + col] = f2bf(acc[t][r] + bb);
            }
        }
    }
    // ---- K projection -> Ks[80][72]
    {
        f32x4 acc[4];
#pragma unroll
        for (int t = 0; t < 4; t++) acc[t] = (f32x4){0.f, 0.f, 0.f, 0.f};
        if (MODE == 2)      proj_g_legacy(Xk, (const float*)Wk_, hs, wave, quad, l16, acc);
        else if (MODE == 3) proj_bb(Xkr, (const unsigned short*)Wk_, hs, wave, quad, l16, acc);
        else                proj_g(Xk, (const unsigned short*)Wk_, hs, wave, quad, l16, acc);
#pragma unroll
        for (int t = 0; t < 4; t++) {
            int col = t * 16 + l16;
            float bb = bk[hs + col];
#pragma unroll
            for (int r = 0; r < 4; r++) {
                int row = wave * 16 + quad * 4 + r;
                Ks[row * 72 + col] = f2bf(acc[t][r] + bb);
            }
        }
    }
    // ---- V projection -> VTs[64][104] transposed; k-rows >=71 stored as 0
    {
        f32x4 acc[4];
#pragma unroll
        for (int t = 0; t < 4; t++) acc[t] = (f32x4){0.f, 0.f, 0.f, 0.f};
        if (MODE == 2)      proj_g_legacy(Xv, (const float*)Wv_, hs, wave, quad, l16, acc);
        else if (MODE == 3) proj_bb(Xvr, (const unsigned short*)Wv_, hs, wave, quad, l16, acc);
        else                proj_g(Xv, (const unsigned short*)Wv_, hs, wave, quad, l16, acc);
#pragma unroll
        for (int t = 0; t < 4; t++) {
            int col = t * 16 + l16;
            float bb = bv[hs + col];
#pragma unroll
            for (int r = 0; r < 4; r++) {
                int row = wave * 16 + quad * 4 + r;
                float v = (row < 71) ? (acc[t][r] + bb) : 0.f;
                VTs[col * 104 + row] = f2bf(v);
            }
        }
    }
    __syncthreads();

    // ---- phase 1: scores = Q K^T / 8   (C-layout regs kept live)
    f32x4 sacc[5];
#pragma unroll
    for (int t = 0; t < 5; t++) sacc[t] = (f32x4){0.f, 0.f, 0.f, 0.f};
#pragma unroll
    for (int kk = 0; kk < 2; kk++) {
        short8 aq = *(const short8*)&Qs[(wave * 16 + l16) * 72 + kk * 32 + quad * 8];
#pragma unroll
        for (int t = 0; t < 5; t++) {
            short8 bk_ = *(const short8*)&Ks[(t * 16 + l16) * 72 + kk * 32 + quad * 8];
            sacc[t] = mfma_bf16(aq, bk_, sacc[t]);
        }
    }
#pragma unroll
    for (int t = 0; t < 5; t++) {
#pragma unroll
        for (int r = 0; r < 4; r++) {
            sacc[t][r] *= 0.125f;
            int row = wave * 16 + quad * 4 + r, col = t * 16 + l16;
            Sb[row * 104 + col] = f2bf(sacc[t][r]);
        }
    }
    __syncthreads();

    // ---- phase 2: H1 = gelu(S @ W1 + b1)
    f32x4 hacc[8];
#pragma unroll
    for (int t = 0; t < 8; t++) hacc[t] = (f32x4){0.f, 0.f, 0.f, 0.f};
#pragma unroll
    for (int kk = 0; kk < 3; kk++) {
        short8 a = *(const short8*)&Sb[(wave * 16 + l16) * 104 + kk * 32 + quad * 8];
        const int k0 = kk * 32 + quad * 8;
#pragma unroll
        for (int t = 0; t < 8; t++) {
            short8 bw;
            if (MODE == 2) {
                const float* wp = (const float*)w1_ + (size_t)k0 * 128 + t * 16 + l16;
#pragma unroll
                for (int j = 0; j < 8; j++)
                    bw[j] = (k0 + j < 71) ? (short)f2bf(wp[(size_t)j * 128]) : (short)0;
            } else {
                bw = *(const short8*)&((const unsigned short*)w1_)[(size_t)(t * 16 + l16) * 96 + k0];
            }
            hacc[t] = mfma_bf16(a, bw, hacc[t]);
        }
    }
#pragma unroll
    for (int t = 0; t < 8; t++) {
        int col = t * 16 + l16;
        float bvf = b1[col];
#pragma unroll
        for (int r = 0; r < 4; r++) {
            float z = hacc[t][r] + bvf;
            float g = 0.5f * z * (1.0f + erff(z * 0.70710678118654752f));
            int row = wave * 16 + quad * 4 + r;
            H1s[row * 136 + col] = f2bf(g);
        }
    }
    __syncthreads();

    // ---- phase 3: G = H1 @ W2
    f32x4 gacc[5];
#pragma unroll
    for (int t = 0; t < 5; t++) gacc[t] = (f32x4){0.f, 0.f, 0.f, 0.f};
#pragma unroll
    for (int kk = 0; kk < 4; kk++) {
        short8 a = *(const short8*)&H1s[(wave * 16 + l16) * 136 + kk * 32 + quad * 8];
        const int k0 = kk * 32 + quad * 8;
#pragma unroll
        for (int t = 0; t < 5; t++) {
            short8 bw;
            if (MODE == 2) {
                const int n = t * 16 + l16;
                const float* wp = (const float*)w2_ + (size_t)k0 * 71 + n;
#pragma unroll
                for (int j = 0; j < 8; j++)
                    bw[j] = (n < 71) ? (short)f2bf(wp[(size_t)j * 71]) : (short)0;
            } else {
                bw = *(const short8*)&((const unsigned short*)w2_)[(size_t)(t * 16 + l16) * 128 + k0];
            }
            gacc[t] = mfma_bf16(a, bw, gacc[t]);
        }
    }
#pragma unroll
    for (int t = 0; t < 5; t++) {
        int col = t * 16 + l16;
        float b2v = (col < 71) ? b2[col] : 0.f;
#pragma unroll
        for (int r = 0; r < 4; r++)
            sacc[t][r] = sacc[t][r] + gacc[t][r] + b2v;
    }

    // ---- phase 4: softmax over cols 0..70 (row spread over 16 lanes x 5 regs)
    bool valid4 = (l16 < 7);
#pragma unroll
    for (int r = 0; r < 4; r++) {
        float mx = -1e30f;
#pragma unroll
        for (int t = 0; t < 5; t++) {
            float v = sacc[t][r];
            if (t == 4 && !valid4) v = -1e30f;
            mx = fmaxf(mx, v);
        }
#pragma unroll
        for (int off = 1; off < 16; off <<= 1) mx = fmaxf(mx, __shfl_xor(mx, off, 16));
        float sum = 0.f;
#pragma unroll
        for (int t = 0; t < 5; t++) {
            float e = (t == 4 && !valid4) ? 0.f : __expf(sacc[t][r] - mx);
            sacc[t][r] = e;
            sum += e;
        }
#pragma unroll
        for (int off = 1; off < 16; off <<= 1) sum += __shfl_xor(sum, off, 16);
        float inv = 1.0f / sum;
#pragma unroll
        for (int t = 0; t < 5; t++) sacc[t][r] *= inv;
    }
#pragma unroll
    for (int t = 0; t < 5; t++) {
#pragma unroll
        for (int r = 0; r < 4; r++) {
            int row = wave * 16 + quad * 4 + r, col = t * 16 + l16;
            Sb[row * 104 + col] = f2bf(sacc[t][r]);   // P; cols 71..95 exact 0
        }
    }
    __syncthreads();

    // ---- phase 5: O = P @ V ; store to AT (bf16) or X2 (fp32)
    f32x4 oacc[4];
#pragma unroll
    for (int t = 0; t < 4; t++) oacc[t] = (f32x4){0.f, 0.f, 0.f, 0.f};
#pragma unroll
    for (int kk = 0; kk < 3; kk++) {
        short8 a = *(const short8*)&Sb[(wave * 16 + l16) * 104 + kk * 32 + quad * 8];
#pragma unroll
        for (int t = 0; t < 4; t++) {
            short8 bvv = *(const short8*)&VTs[(t * 16 + l16) * 104 + kk * 32 + quad * 8];
            oacc[t] = mfma_bf16(a, bvv, oacc[t]);
        }
    }
#pragma unroll
    for (int r = 0; r < 4; r++) {
        int l = wave * 16 + quad * 4 + r;
        if (l < 71) {
#pragma unroll
            for (int t = 0; t < 4; t++) {
                int col = hs + t * 16 + l16;
                if (MODE == 1 || MODE == 3)
                    AT[(size_t)(b * 71 + l) * 512 + col] = f2bf(oacc[t][r]);
                else
                    X2[(size_t)(b * 71 + l) * 512 + col] = oacc[t][r];
            }
        }
    }
}

// ---------------------------------------------------------------------------
// Kernel 2: output projection v2. 1136 blocks of 128x128, bijective XCD
// swizzle, 8 waves x (32x64)/wave, even/odd double-buffered register loads.
// ---------------------------------------------------------------------------
__global__ __launch_bounds__(512) void gemm_o_bf16_v2(
    const unsigned short* __restrict__ WoT,  // [512 n][512 k] bf16
    const float* __restrict__ bo,            // [512] fp32
    const unsigned short* __restrict__ AT,   // [36352][512] bf16
    float* __restrict__ Y)                   // [36352][512] fp32 out
{
    const int tid  = threadIdx.x;
    const int wave = tid >> 6, lane = tid & 63;
    const int quad = lane >> 4, l16 = lane & 15;
    // bijective XCD swizzle: 1136 = 8 * 142
    const int g   = blockIdx.x;
    const int wg  = (g & 7) * 142 + (g >> 3);
    const int m0  = (wg >> 2) * 128;
    const int n0  = (wg & 3) * 128;
    const int wm  = (wave >> 1) * 32, wn = (wave & 1) * 64;

    f32x4 acc[2][4];
#pragma unroll
    for (int i = 0; i < 2; i++)
#pragma unroll
        for (int j = 0; j < 4; j++) acc[i][j] = (f32x4){0.f, 0.f, 0.f, 0.f};

#define LDA(kk,i) (*(const short8*)&AT[(size_t)(m0 + wm + (i) * 16 + l16) * 512 + (kk) * 32 + quad * 8])
#define LDB(kk,j) (*(const short8*)&WoT[(size_t)(n0 + wn + (j) * 16 + l16) * 512 + (kk) * 32 + quad * 8])

    short8 aE[2], bE[4], aO[2], bO[4];
#pragma unroll
    for (int i = 0; i < 2; i++) aE[i] = LDA(0, i);
#pragma unroll
    for (int j = 0; j < 4; j++) bE[j] = LDB(0, j);

#pragma unroll
    for (int kp = 0; kp < 8; ++kp) {
        const int ko = 2 * kp + 1;
#pragma unroll
        for (int i = 0; i < 2; i++) aO[i] = LDA(ko, i);
#pragma unroll
        for (int j = 0; j < 4; j++) bO[j] = LDB(ko, j);
#pragma unroll
        for (int i = 0; i < 2; i++)
#pragma unroll
            for (int j = 0; j < 4; j++)
                acc[i][j] = mfma_bf16(aE[i], bE[j], acc[i][j]);
        if (kp < 7) {
            const int ke = 2 * kp + 2;
#pragma unroll
            for (int i = 0; i < 2; i++) aE[i] = LDA(ke, i);
#pragma unroll
            for (int j = 0; j < 4; j++) bE[j] = LDB(ke, j);
        }
#pragma unroll
        for (int i = 0; i < 2; i++)
#pragma unroll
            for (int j = 0; j < 4; j++)
                acc[i][j] = mfma_bf16(aO[i], bO[j], acc[i][j]);
    }
#undef LDA
#undef LDB

#pragma unroll
    for (int j = 0; j < 4; j++) {
        int gcol = n0 + wn + j * 16 + l16;
        float bvf = bo[gcol];
#pragma unroll
        for (int i = 0; i < 2; i++) {
#pragma unroll
            for (int r = 0; r < 4; r++) {
                int grow = m0 + wm + i * 16 + quad * 4 + r;
                Y[(size_t)grow * 512 + gcol] = acc[i][j][r] + bvf;
            }
        }
    }
}

// ---------------------------------------------------------------------------
// Kernel 2b: in-place on fp32 Y. WMODE 0: bf16 WoT. WMODE 1: fp32 Wo gather.
// ---------------------------------------------------------------------------
template<int WMODE>
__global__ __launch_bounds__(512, 2) void gemm_o_inplace(
    const void* __restrict__ Wo_,
    const float* __restrict__ bo,
    float* __restrict__ Y)                   // [36352][512] fp32, in/out
{
    const int tid  = threadIdx.x;
    const int wave = tid >> 6, lane = tid & 63;
    const int quad = lane >> 4, l16 = lane & 15;
    const int m0 = blockIdx.x * 128;
    const int wm = (wave >> 2) * 64, wn = (wave & 3) * 128;

    f32x4 acc[4][8];
#pragma unroll
    for (int i = 0; i < 4; i++)
#pragma unroll
        for (int j = 0; j < 8; j++) acc[i][j] = (f32x4){0.f, 0.f, 0.f, 0.f};

    for (int kk = 0; kk < 16; ++kk) {
        const int k0 = kk * 32 + quad * 8;
        short8 af[4];
#pragma unroll
        for (int i = 0; i < 4; i++) {
            const float* p = Y + (size_t)(m0 + wm + i * 16 + l16) * 512 + k0;
            short8 a;
#pragma unroll
            for (int j = 0; j < 8; j++) a[j] = (short)f2bf(p[j]);
            af[i] = a;
        }
        short8 bfr[8];
#pragma unroll
        for (int j = 0; j < 8; j++) {
            if (WMODE == 1) {
                const float* wp = (const float*)Wo_ + (size_t)k0 * 512 + wn + j * 16 + l16;
                short8 bw;
#pragma unroll
                for (int e = 0; e < 8; e++) bw[e] = (short)f2bf(wp[(size_t)e * 512]);
                bfr[j] = bw;
            } else {
                bfr[j] = *(const short8*)&((const unsigned short*)Wo_)[(size_t)(wn + j * 16 + l16) * 512 + k0];
            }
        }
#pragma unroll
        for (int i = 0; i < 4; i++)
#pragma unroll
            for (int j = 0; j < 8; j++)
                acc[i][j] = mfma_bf16(af[i], bfr[j], acc[i][j]);
    }

    __syncthreads();   // all A-reads in this block complete before any write

#pragma unroll
    for (int j = 0; j < 8; j++) {
        int gcol = wn + j * 16 + l16;
        float bvf = bo[gcol];
#pragma unroll
        for (int i = 0; i < 4; i++) {
#pragma unroll
            for (int r = 0; r < 4; r++) {
                int grow = m0 + wm + i * 16 + quad * 4 + r;
                Y[(size_t)grow * 512 + gcol] = acc[i][j][r] + bvf;
            }
        }
    }
}

extern "C" void kernel_launch(void* const* d_in, const int* in_sizes, int n_in,
                              void* d_out, int out_size, void* d_ws, size_t ws_size,
                              hipStream_t stream) {
    (void)in_sizes; (void)n_in; (void)out_size;
    const float* query = (const float*)d_in[0];
    const float* key_  = (const float*)d_in[1];
    const float* value = (const float*)d_in[2];
    const float* Wq = (const float*)d_in[3];
    const float* bq = (const float*)d_in[4];
    const float* Wk = (const float*)d_in[5];
    const float* bk = (const float*)d_in[6];
    const float* Wv = (const float*)d_in[7];
    const float* bv = (const float*)d_in[8];
    const float* Wo = (const float*)d_in[9];
    const float* bo = (const float*)d_in[10];
    const float* w1 = (const float*)d_in[11];
    const float* b1 = (const float*)d_in[12];
    const float* w2 = (const float*)d_in[13];
    const float* b2 = (const float*)d_in[14];

    unsigned short* wsT = (unsigned short*)d_ws;
    unsigned short* WqT = wsT;
    unsigned short* WkT = wsT + 262144;
    unsigned short* WvT = wsT + 524288;
    unsigned short* WoT = wsT + 786432;
    unsigned short* w1T = wsT + WS_W1T_OFF;
    unsigned short* w2T = wsT + WS_W2T_OFF;
    unsigned short* AT  = wsT + WS_AT_OFF;
    unsigned short* Xqb = wsT + WS_XQ_OFF;
    unsigned short* Xkb = wsT + WS_XK_OFF;
    unsigned short* Xvb = wsT + WS_XV_OFF;
    const size_t NEED_W    = (size_t)WS_AT_OFF * 2;                          // ~2.1 MB
    const size_t NEED_BIG  = ((size_t)WS_AT_OFF + (size_t)MM * 512) * 2;     // ~39.4 MB
    const size_t NEED_FULL = ((size_t)WS_AT_OFF + 4 * (size_t)MM * 512) * 2; // ~151 MB

    float* X2 = (float*)d_out;

    if (d_ws == nullptr || ws_size < NEED_W) {
        // LEGACY path (verified baseline): zero workspace bytes used.
        attn_fused<2><<<4096, 320, 0, stream>>>(query, key_, value,
                                                nullptr, nullptr, nullptr,
                                                Wq, bq, Wk, bk, Wv, bv,
                                                w1, b1, w2, b2, X2, nullptr);
        gemm_o_inplace<1><<<284, 512, 0, stream>>>(Wo, bo, X2);
        return;
    }

    wcvt512<<<256, 256, 0, stream>>>(Wq, Wk, Wv, Wo, WqT, WkT, WvT, WoT);
    sfcvt<<<1, 256, 0, stream>>>(w1, w2, w1T, w2T);

    if (ws_size >= NEED_FULL) {
        xcvt<<<2048, 256, 0, stream>>>(query, key_, value, Xqb, Xkb, Xvb);
        attn_fused<3><<<4096, 320, 0, stream>>>(query, key_, value,
                                                Xqb, Xkb, Xvb,
                                                WqT, bq, WkT, bk, WvT, bv,
                                                w1T, b1, w2T, b2, nullptr, AT);
        gemm_o_bf16_v2<<<1136, 512, 0, stream>>>(WoT, bo, AT, X2);
    } else if (ws_size >= NEED_BIG) {
        attn_fused<1><<<4096, 320, 0, stream>>>(query, key_, value,
                                                nullptr, nullptr, nullptr,
                                                WqT, bq, WkT, bk, WvT, bv,
                                                w1T, b1, w2T, b2, nullptr, AT);
        gemm_o_bf16_v2<<<1136, 512, 0, stream>>>(WoT, bo, AT, X2);
    } else {
        attn_fused<0><<<4096, 320, 0, stream>>>(query, key_, value,
                                                nullptr, nullptr, nullptr,
                                                WqT, bq, WkT, bk, WvT, bv,
                                                w1T, b1, w2T, b2, X2, nullptr);
        gemm_o_inplace<0><<<284, 512, 0, stream>>>(WoT, bo, X2);
    }
}

// Round 5
// 897.278 us; speedup vs baseline: 1.3052x; 1.2123x over previous
//
#include <hip/hip_runtime.h>
#include <math.h>

#define Bb 512
#define Ll 71
#define Dd 512
#define Hh 8
#define DH 64
#define MM (Bb*Ll)   // 36352 = 284 * 128

typedef __attribute__((ext_vector_type(8))) short short8;
typedef __attribute__((ext_vector_type(4))) float f32x4;

static __device__ __forceinline__ f32x4 mfma_bf16(short8 a, short8 b, f32x4 c) {
    return __builtin_amdgcn_mfma_f32_16x16x32_bf16(a, b, c, 0, 0, 0);
}

// fp32 -> bf16 with round-to-nearest-even
static __device__ __forceinline__ unsigned short f2bf(float f) {
    union { float f; unsigned u; } v; v.f = f;
    unsigned r = v.u + 0x7FFFu + ((v.u >> 16) & 1u);
    return (unsigned short)(r >> 16);
}

// ---------------------------------------------------------------------------
// ws layout (ushort elements):
//   0        WqT  bf16 [512 n][512 k]
//   262144   WkT  bf16 [512][512]
//   524288   WvT  bf16 [512][512]
//   786432   WoT  bf16 [512][512]
//   1048576  w1T  bf16 [128 n][96 k]   (k >= 71 zeroed)
//   1060864  w2T  bf16 [80 n][128 k]   (n >= 71 rows zeroed)
//   1071104  AT   bf16 [36352][512]    (attention output)
//   19683328 Qp   bf16 [36352][512]    (projected Q, bias added)
//   38295552 Kp   bf16 [36352][512]
//   56907776 Vp   bf16 [36352][512]
// ---------------------------------------------------------------------------
#define WS_W1T_OFF 1048576
#define WS_W2T_OFF 1060864
#define WS_AT_OFF  1071104
#define WS_QP_OFF  19683328
#define WS_KP_OFF  38295552
#define WS_VP_OFF  56907776

// Transpose+convert one 64x64 tile of a 512x512 fp32 weight into bf16 [n][k].
__global__ __launch_bounds__(256) void wcvt512(
    const float* __restrict__ W0, const float* __restrict__ W1,
    const float* __restrict__ W2, const float* __restrict__ W3,
    unsigned short* __restrict__ T0, unsigned short* __restrict__ T1,
    unsigned short* __restrict__ T2, unsigned short* __restrict__ T3)
{
    __shared__ unsigned short t[64][72];
    const int m    = blockIdx.x >> 6;
    const int tile = blockIdx.x & 63;
    const float* W = (m == 0) ? W0 : (m == 1) ? W1 : (m == 2) ? W2 : W3;
    unsigned short* T = (m == 0) ? T0 : (m == 1) ? T1 : (m == 2) ? T2 : T3;
    const int tk = (tile >> 3) * 64, tn = (tile & 7) * 64;
    const int ln = threadIdx.x & 63, lr = threadIdx.x >> 6;
#pragma unroll
    for (int r = lr; r < 64; r += 4)
        t[ln][r] = f2bf(W[(size_t)(tk + r) * 512 + tn + ln]);
    __syncthreads();
#pragma unroll
    for (int r = lr; r < 64; r += 4)
        T[(size_t)(tn + r) * 512 + tk + ln] = t[r][ln];
}

// Convert w1 [71][128] -> w1T [128][96] (k>=71 zero) and
//         w2 [128][71] -> w2T [80][128] (n>=71 rows zero).
__global__ __launch_bounds__(256) void sfcvt(
    const float* __restrict__ w1, const float* __restrict__ w2,
    unsigned short* __restrict__ w1T, unsigned short* __restrict__ w2T)
{
    const int tid = threadIdx.x;
    for (int i = tid; i < 128 * 96; i += 256) {
        int n = i / 96, k = i % 96;
        w1T[i] = (k < 71) ? f2bf(w1[(size_t)k * 128 + n]) : (unsigned short)0;
    }
    for (int i = tid; i < 80 * 128; i += 256) {
        int n = i / 128, k = i % 128;
        w2T[i] = (n < 71) ? f2bf(w2[(size_t)k * 71 + n]) : (unsigned short)0;
    }
}

// load 8 fp32 and convert to a bf16 short8 fragment
static __device__ __forceinline__ short8 lda_cvt(const float* __restrict__ p) {
    const f32x4 p0 = *(const f32x4*)p;
    const f32x4 p1 = *(const f32x4*)(p + 4);
    short8 a;
#pragma unroll
    for (int j = 0; j < 4; j++) {
        a[j]     = (short)f2bf(p0[j]);
        a[4 + j] = (short)f2bf(p1[j]);
    }
    return a;
}

// ---------------------------------------------------------------------------
// QKV projection GEMM: 3 x [36352,512]@[512,512] + bias -> bf16.
// 3408 blocks (3 mats x 284 mtiles x 4 ntiles), 512 thr, 128x128 tile,
// 8 waves x 32x64, even/odd register double-buffer, bijective XCD swizzle.
// ---------------------------------------------------------------------------
__global__ __launch_bounds__(512) void qkv_gemm(
    const float* __restrict__ X0, const float* __restrict__ X1,
    const float* __restrict__ X2i,
    const unsigned short* __restrict__ W0T,
    const unsigned short* __restrict__ W1T,
    const unsigned short* __restrict__ W2T,
    const float* __restrict__ bb0, const float* __restrict__ bb1,
    const float* __restrict__ bb2,
    unsigned short* __restrict__ O0, unsigned short* __restrict__ O1,
    unsigned short* __restrict__ O2)
{
    const int tid  = threadIdx.x;
    const int wave = tid >> 6, lane = tid & 63;
    const int quad = lane >> 4, l16 = lane & 15;
    // bijective XCD swizzle: 3408 = 8 * 426
    const int g  = blockIdx.x;
    const int wg = (g & 7) * 426 + (g >> 3);
    const int mat = wg / 1136;
    const int r_  = wg - mat * 1136;
    const int m0 = (r_ >> 2) * 128, n0 = (r_ & 3) * 128;
    const float* X = (mat == 0) ? X0 : (mat == 1) ? X1 : X2i;
    const unsigned short* WT = (mat == 0) ? W0T : (mat == 1) ? W1T : W2T;
    const float* bias = (mat == 0) ? bb0 : (mat == 1) ? bb1 : bb2;
    unsigned short* O = (mat == 0) ? O0 : (mat == 1) ? O1 : O2;

    const int wm = (wave >> 1) * 32, wn = (wave & 1) * 64;

    f32x4 acc[2][4];
#pragma unroll
    for (int i = 0; i < 2; i++)
#pragma unroll
        for (int j = 0; j < 4; j++) acc[i][j] = (f32x4){0.f, 0.f, 0.f, 0.f};

#define QLDA(kk,i) lda_cvt(X + (size_t)(m0 + wm + (i) * 16 + l16) * 512 + (kk) * 32 + quad * 8)
#define QLDB(kk,j) (*(const short8*)&WT[(size_t)(n0 + wn + (j) * 16 + l16) * 512 + (kk) * 32 + quad * 8])

    short8 aE[2], bE[4], aO[2], bO[4];
#pragma unroll
    for (int i = 0; i < 2; i++) aE[i] = QLDA(0, i);
#pragma unroll
    for (int j = 0; j < 4; j++) bE[j] = QLDB(0, j);

#pragma unroll
    for (int kp = 0; kp < 8; ++kp) {
        const int ko = 2 * kp + 1;
#pragma unroll
        for (int i = 0; i < 2; i++) aO[i] = QLDA(ko, i);
#pragma unroll
        for (int j = 0; j < 4; j++) bO[j] = QLDB(ko, j);
#pragma unroll
        for (int i = 0; i < 2; i++)
#pragma unroll
            for (int j = 0; j < 4; j++)
                acc[i][j] = mfma_bf16(aE[i], bE[j], acc[i][j]);
        if (kp < 7) {
            const int ke = 2 * kp + 2;
#pragma unroll
            for (int i = 0; i < 2; i++) aE[i] = QLDA(ke, i);
#pragma unroll
            for (int j = 0; j < 4; j++) bE[j] = QLDB(ke, j);
        }
#pragma unroll
        for (int i = 0; i < 2; i++)
#pragma unroll
            for (int j = 0; j < 4; j++)
                acc[i][j] = mfma_bf16(aO[i], bO[j], acc[i][j]);
    }
#undef QLDA
#undef QLDB

#pragma unroll
    for (int j = 0; j < 4; j++) {
        int gcol = n0 + wn + j * 16 + l16;
        float bvf = bias[gcol];
#pragma unroll
        for (int i = 0; i < 2; i++) {
#pragma unroll
            for (int r = 0; r < 4; r++) {
                int grow = m0 + wm + i * 16 + quad * 4 + r;
                O[(size_t)grow * 512 + gcol] = f2bf(acc[i][j][r] + bvf);
            }
        }
    }
}

// ---------------------------------------------------------------------------
// Attention-only kernel per (b,h). 320 thr = 5 waves. Q/K fragments load
// directly global->reg (L2-resident bf16); V scattered to LDS transposed.
// Writes bf16 AT.
// ---------------------------------------------------------------------------
__global__ __launch_bounds__(320) void attn2(
    const unsigned short* __restrict__ Qp,
    const unsigned short* __restrict__ Kp,
    const unsigned short* __restrict__ Vp,
    const unsigned short* __restrict__ w1T,  // [128][96] bf16
    const float* __restrict__ b1,            // [128]
    const unsigned short* __restrict__ w2T,  // [80][128] bf16
    const float* __restrict__ b2,            // [71]
    unsigned short* __restrict__ AT)         // [36352][512] bf16
{
    __shared__ __align__(16) unsigned short smem[25856];
    unsigned short* VTs = smem;              // [64][104]  V^T, k-contig
    unsigned short* Sb  = smem + 6656;       // [80][104]
    unsigned short* H1s = smem + 14976;      // [80][136]

    const int tid = threadIdx.x;
    const int wave = tid >> 6, lane = tid & 63;
    const int quad = lane >> 4, l16 = lane & 15;
    const int x = blockIdx.x;
    const int b = ((x >> 6) << 3) | (x & 7);   // XCD-aware remap
    const int h = (x >> 3) & 7;
    const int hs = h * 64;
    const unsigned short* Qr = Qp + (size_t)(b * 71) * 512 + hs;
    const unsigned short* Kr = Kp + (size_t)(b * 71) * 512 + hs;
    const unsigned short* Vr = Vp + (size_t)(b * 71) * 512 + hs;

    // zero pads
    for (int i = tid; i < 1600; i += 320) {   // VTs k-cols [71,96) all n
        int n = i / 25, c = 71 + (i % 25);
        VTs[n * 104 + c] = 0;
    }
    for (int i = tid; i < 1280; i += 320) {   // Sb cols [80,96)
        int r = i >> 4, c = 80 + (i & 15);
        Sb[r * 104 + c] = 0;
    }
    // V scatter -> VTs[col][row]
    for (int i = tid; i < 568; i += 320) {
        int row = i >> 3, c8 = i & 7;
        short8 v = *(const short8*)&Vr[(size_t)row * 512 + c8 * 8];
#pragma unroll
        for (int e = 0; e < 8; e++)
            VTs[(c8 * 8 + e) * 104 + row] = (unsigned short)v[e];
    }
    __syncthreads();

    // ---- phase 1: scores = Q K^T / 8, Q/K frags direct from global
    f32x4 sacc[5];
#pragma unroll
    for (int t = 0; t < 5; t++) sacc[t] = (f32x4){0.f, 0.f, 0.f, 0.f};
    const int arow = wave * 16 + l16;
    const bool aok = (arow < 71);
#pragma unroll
    for (int kk = 0; kk < 2; kk++) {
        short8 aq = aok ? *(const short8*)&Qr[(size_t)arow * 512 + kk * 32 + quad * 8]
                        : (short8){0,0,0,0,0,0,0,0};
#pragma unroll
        for (int t = 0; t < 5; t++) {
            const int brow = t * 16 + l16;
            short8 bk_ = (brow < 71)
                ? *(const short8*)&Kr[(size_t)brow * 512 + kk * 32 + quad * 8]
                : (short8){0,0,0,0,0,0,0,0};
            sacc[t] = mfma_bf16(aq, bk_, sacc[t]);
        }
    }
#pragma unroll
    for (int t = 0; t < 5; t++) {
#pragma unroll
        for (int r = 0; r < 4; r++) {
            sacc[t][r] *= 0.125f;
            int row = wave * 16 + quad * 4 + r, col = t * 16 + l16;
            Sb[row * 104 + col] = f2bf(sacc[t][r]);
        }
    }
    __syncthreads();

    // ---- phase 2: H1 = gelu(S @ W1 + b1)
    f32x4 hacc[8];
#pragma unroll
    for (int t = 0; t < 8; t++) hacc[t] = (f32x4){0.f, 0.f, 0.f, 0.f};
#pragma unroll
    for (int kk = 0; kk < 3; kk++) {
        short8 a = *(const short8*)&Sb[(wave * 16 + l16) * 104 + kk * 32 + quad * 8];
        const int k0 = kk * 32 + quad * 8;
#pragma unroll
        for (int t = 0; t < 8; t++) {
            short8 bw = *(const short8*)&w1T[(size_t)(t * 16 + l16) * 96 + k0];
            hacc[t] = mfma_bf16(a, bw, hacc[t]);
        }
    }
#pragma unroll
    for (int t = 0; t < 8; t++) {
        int col = t * 16 + l16;
        float bvf = b1[col];
#pragma unroll
        for (int r = 0; r < 4; r++) {
            float z = hacc[t][r] + bvf;
            float g = 0.5f * z * (1.0f + erff(z * 0.70710678118654752f));
            int row = wave * 16 + quad * 4 + r;
            H1s[row * 136 + col] = f2bf(g);
        }
    }
    __syncthreads();

    // ---- phase 3: G = H1 @ W2
    f32x4 gacc[5];
#pragma unroll
    for (int t = 0; t < 5; t++) gacc[t] = (f32x4){0.f, 0.f, 0.f, 0.f};
#pragma unroll
    for (int kk = 0; kk < 4; kk++) {
        short8 a = *(const short8*)&H1s[(wave * 16 + l16) * 136 + kk * 32 + quad * 8];
        const int k0 = kk * 32 + quad * 8;
#pragma unroll
        for (int t = 0; t < 5; t++) {
            short8 bw = *(const short8*)&w2T[(size_t)(t * 16 + l16) * 128 + k0];
            gacc[t] = mfma_bf16(a, bw, gacc[t]);
        }
    }
#pragma unroll
    for (int t = 0; t < 5; t++) {
        int col = t * 16 + l16;
        float b2v = (col < 71) ? b2[col] : 0.f;
#pragma unroll
        for (int r = 0; r < 4; r++)
            sacc[t][r] = sacc[t][r] + gacc[t][r] + b2v;
    }

    // ---- phase 4: softmax over cols 0..70
    bool valid4 = (l16 < 7);
#pragma unroll
    for (int r = 0; r < 4; r++) {
        float mx = -1e30f;
#pragma unroll
        for (int t = 0; t < 5; t++) {
            float v = sacc[t][r];
            if (t == 4 && !valid4) v = -1e30f;
            mx = fmaxf(mx, v);
        }
#pragma unroll
        for (int off = 1; off < 16; off <<= 1) mx = fmaxf(mx, __shfl_xor(mx, off, 16));
        float sum = 0.f;
#pragma unroll
        for (int t = 0; t < 5; t++) {
            float e = (t == 4 && !valid4) ? 0.f : __expf(sacc[t][r] - mx);
            sacc[t][r] = e;
            sum += e;
        }
#pragma unroll
        for (int off = 1; off < 16; off <<= 1) sum += __shfl_xor(sum, off, 16);
        float inv = 1.0f / sum;
#pragma unroll
        for (int t = 0; t < 5; t++) sacc[t][r] *= inv;
    }
#pragma unroll
    for (int t = 0; t < 5; t++) {
#pragma unroll
        for (int r = 0; r < 4; r++) {
            int row = wave * 16 + quad * 4 + r, col = t * 16 + l16;
            Sb[row * 104 + col] = f2bf(sacc[t][r]);   // P; cols 71..95 exact 0
        }
    }
    __syncthreads();

    // ---- phase 5: O = P @ V -> AT bf16
    f32x4 oacc[4];
#pragma unroll
    for (int t = 0; t < 4; t++) oacc[t] = (f32x4){0.f, 0.f, 0.f, 0.f};
#pragma unroll
    for (int kk = 0; kk < 3; kk++) {
        short8 a = *(const short8*)&Sb[(wave * 16 + l16) * 104 + kk * 32 + quad * 8];
#pragma unroll
        for (int t = 0; t < 4; t++) {
            short8 bvv = *(const short8*)&VTs[(t * 16 + l16) * 104 + kk * 32 + quad * 8];
            oacc[t] = mfma_bf16(a, bvv, oacc[t]);
        }
    }
#pragma unroll
    for (int r = 0; r < 4; r++) {
        int l = wave * 16 + quad * 4 + r;
        if (l < 71) {
#pragma unroll
            for (int t = 0; t < 4; t++)
                AT[(size_t)(b * 71 + l) * 512 + hs + t * 16 + l16] = f2bf(oacc[t][r]);
        }
    }
}

// ---------------------------------------------------------------------------
// Fallback projection helpers + fused kernel (verified round-2 paths).
// ---------------------------------------------------------------------------
static __device__ __forceinline__ void proj_g(
    const float* __restrict__ Xrows,
    const unsigned short* __restrict__ WT,
    int hs, int wave, int quad, int l16, f32x4 acc[4])
{
    const int arow = wave * 16 + l16;
    const bool ok = (arow < 71);
    const float* ap = Xrows + (size_t)arow * 512 + quad * 8;
    const unsigned short* w0 = WT + (size_t)(hs + l16) * 512 + quad * 8;
#pragma unroll 4
    for (int kk = 0; kk < 16; ++kk) {
        short8 a;
        if (ok) {
            const f32x4 p0 = *(const f32x4*)(ap + (size_t)kk * 32);
            const f32x4 p1 = *(const f32x4*)(ap + (size_t)kk * 32 + 4);
#pragma unroll
            for (int j = 0; j < 4; j++) {
                a[j]     = (short)f2bf(p0[j]);
                a[4 + j] = (short)f2bf(p1[j]);
            }
        } else {
            a = (short8){0,0,0,0,0,0,0,0};
        }
#pragma unroll
        for (int t = 0; t < 4; t++) {
            short8 bw = *(const short8*)(w0 + (size_t)t * (16 * 512) + kk * 32);
            acc[t] = mfma_bf16(a, bw, acc[t]);
        }
    }
}

static __device__ __forceinline__ void proj_g_legacy(
    const float* __restrict__ Xrows,
    const float* __restrict__ W,
    int hs, int wave, int quad, int l16, f32x4 acc[4])
{
    const int arow = wave * 16 + l16;
    const bool ok = (arow < 71);
    const float* ap = Xrows + (size_t)arow * 512 + quad * 8;
    const int nb = hs + l16;
#pragma unroll 2
    for (int kk = 0; kk < 16; ++kk) {
        short8 a;
        if (ok) {
            const float* p = ap + (size_t)kk * 32;
#pragma unroll
            for (int j = 0; j < 8; j++) a[j] = (short)f2bf(p[j]);
        } else {
            a = (short8){0,0,0,0,0,0,0,0};
        }
        const int k0 = kk * 32 + quad * 8;
#pragma unroll
        for (int t = 0; t < 4; t++) {
            const float* wp = W + (size_t)k0 * 512 + nb + t * 16;
            short8 bw;
#pragma unroll
            for (int j = 0; j < 8; j++) bw[j] = (short)f2bf(wp[(size_t)j * 512]);
            acc[t] = mfma_bf16(a, bw, acc[t]);
        }
    }
}

// MODE 0: bf16 W, fp32 X, fp32 out.  MODE 1: bf16 W, fp32 X, bf16 out.
// MODE 2: legacy fp32 everything.
template<int MODE>
__global__ __launch_bounds__(320) void attn_fused(
    const float* __restrict__ query,
    const float* __restrict__ key_,
    const float* __restrict__ value,
    const void* __restrict__ Wq_, const float* __restrict__ bq,
    const void* __restrict__ Wk_, const float* __restrict__ bk,
    const void* __restrict__ Wv_, const float* __restrict__ bv,
    const void* __restrict__ w1_,
    const float* __restrict__ b1,
    const void* __restrict__ w2_,
    const float* __restrict__ b2,
    float* __restrict__ X2,
    unsigned short* __restrict__ AT)
{
    __shared__ __align__(16) unsigned short smem[26496];
    unsigned short* Qs  = smem;              // [80][72]
    unsigned short* Ks  = smem + 5760;       // [80][72]
    unsigned short* H1s = smem;              // [80][136] overlays Qs+Ks
    unsigned short* VTs = smem + 11520;      // [64][104]
    unsigned short* Sb  = smem + 18176;      // [80][104]

    const int tid = threadIdx.x;
    const int wave = tid >> 6, lane = tid & 63;
    const int quad = lane >> 4, l16 = lane & 15;
    const int x = blockIdx.x;
    const int b = ((x >> 6) << 3) | (x & 7);
    const int h = (x >> 3) & 7;
    const int hs = h * 64;
    const float* Xq = query + (size_t)(b * 71) * 512;
    const float* Xk = key_  + (size_t)(b * 71) * 512;
    const float* Xv = value + (size_t)(b * 71) * 512;

    for (int i = tid; i < 1280; i += 320) {
        int r = i >> 4, c = 80 + (i & 15);
        Sb[r * 104 + c] = 0;
    }
    for (int i = tid; i < 1024; i += 320) {
        int n = i >> 4, c = 80 + (i & 15);
        VTs[n * 104 + c] = 0;
    }

    {
        f32x4 acc[4];
#pragma unroll
        for (int t = 0; t < 4; t++) acc[t] = (f32x4){0.f, 0.f, 0.f, 0.f};
        if (MODE == 2) proj_g_legacy(Xq, (const float*)Wq_, hs, wave, quad, l16, acc);
        else           proj_g(Xq, (const unsigned short*)Wq_, hs, wave, quad, l16, acc);
#pragma unroll
        for (int t = 0; t < 4; t++) {
            int col = t * 16 + l16;
            float bb = bq[hs + col];
#pragma unroll
            for (int r = 0; r < 4; r++) {
                int row = wave * 16 + quad * 4 + r;
                Qs[row * 72 + col] = f2bf(acc[t][r] + bb);
            }
        }
    }
    {
        f32x4 acc[4];
#pragma unroll
        for (int t = 0; t < 4; t++) acc[t] = (f32x4){0.f, 0.f, 0.f, 0.f};
        if (MODE == 2) proj_g_legacy(Xk, (const float*)Wk_, hs, wave, quad, l16, acc);
        else           proj_g(Xk, (const unsigned short*)Wk_, hs, wave, quad, l16, acc);
#pragma unroll
        for (int t = 0; t < 4; t++) {
            int col = t * 16 + l16;
            float bb = bk[hs + col];
#pragma unroll
            for (int r = 0; r < 4; r++) {
                int row = wave * 16 + quad * 4 + r;
                Ks[row * 72 + col] = f2bf(acc[t][r] + bb);
            }
        }
    }
    {
        f32x4 acc[4];
#pragma unroll
        for (int t = 0; t < 4; t++) acc[t] = (f32x4){0.f, 0.f, 0.f, 0.f};
        if (MODE == 2) proj_g_legacy(Xv, (const float*)Wv_, hs, wave, quad, l16, acc);
        else           proj_g(Xv, (const unsigned short*)Wv_, hs, wave, quad, l16, acc);
#pragma unroll
        for (int t = 0; t < 4; t++) {
            int col = t * 16 + l16;
            float bb = bv[hs + col];
#pragma unroll
            for (int r = 0; r < 4; r++) {
                int row = wave * 16 + quad * 4 + r;
                float v = (row < 71) ? (acc[t][r] + bb) : 0.f;
                VTs[col * 104 + row] = f2bf(v);
            }
        }
    }
    __syncthreads();

    f32x4 sacc[5];
#pragma unroll
    for (int t = 0; t < 5; t++) sacc[t] = (f32x4){0.f, 0.f, 0.f, 0.f};
#pragma unroll
    for (int kk = 0; kk < 2; kk++) {
        short8 aq = *(const short8*)&Qs[(wave * 16 + l16) * 72 + kk * 32 + quad * 8];
#pragma unroll
        for (int t = 0; t < 5; t++) {
            short8 bk_ = *(const short8*)&Ks[(t * 16 + l16) * 72 + kk * 32 + quad * 8];
            sacc[t] = mfma_bf16(aq, bk_, sacc[t]);
        }
    }
#pragma unroll
    for (int t = 0; t < 5; t++) {
#pragma unroll
        for (int r = 0; r < 4; r++) {
            sacc[t][r] *= 0.125f;
            int row = wave * 16 + quad * 4 + r, col = t * 16 + l16;
            Sb[row * 104 + col] = f2bf(sacc[t][r]);
        }
    }
    __syncthreads();

    f32x4 hacc[8];
#pragma unroll
    for (int t = 0; t < 8; t++) hacc[t] = (f32x4){0.f, 0.f, 0.f, 0.f};
#pragma unroll
    for (int kk = 0; kk < 3; kk++) {
        short8 a = *(const short8*)&Sb[(wave * 16 + l16) * 104 + kk * 32 + quad * 8];
        const int k0 = kk * 32 + quad * 8;
#pragma unroll
        for (int t = 0; t < 8; t++) {
            short8 bw;
            if (MODE == 2) {
                const float* wp = (const float*)w1_ + (size_t)k0 * 128 + t * 16 + l16;
#pragma unroll
                for (int j = 0; j < 8; j++)
                    bw[j] = (k0 + j < 71) ? (short)f2bf(wp[(size_t)j * 128]) : (short)0;
            } else {
                bw = *(const short8*)&((const unsigned short*)w1_)[(size_t)(t * 16 + l16) * 96 + k0];
            }
            hacc[t] = mfma_bf16(a, bw, hacc[t]);
        }
    }
#pragma unroll
    for (int t = 0; t < 8; t++) {
        int col = t * 16 + l16;
        float bvf = b1[col];
#pragma unroll
        for (int r = 0; r < 4; r++) {
            float z = hacc[t][r] + bvf;
            float g = 0.5f * z * (1.0f + erff(z * 0.70710678118654752f));
            int row = wave * 16 + quad * 4 + r;
            H1s[row * 136 + col] = f2bf(g);
        }
    }
    __syncthreads();

    f32x4 gacc[5];
#pragma unroll
    for (int t = 0; t < 5; t++) gacc[t] = (f32x4){0.f, 0.f, 0.f, 0.f};
#pragma unroll
    for (int kk = 0; kk < 4; kk++) {
        short8 a = *(const short8*)&H1s[(wave * 16 + l16) * 136 + kk * 32 + quad * 8];
        const int k0 = kk * 32 + quad * 8;
#pragma unroll
        for (int t = 0; t < 5; t++) {
            short8 bw;
            if (MODE == 2) {
                const int n = t * 16 + l16;
                const float* wp = (const float*)w2_ + (size_t)k0 * 71 + n;
#pragma unroll
                for (int j = 0; j < 8; j++)
                    bw[j] = (n < 71) ? (short)f2bf(wp[(size_t)j * 71]) : (short)0;
            } else {
                bw = *(const short8*)&((const unsigned short*)w2_)[(size_t)(t * 16 + l16) * 128 + k0];
            }
            gacc[t] = mfma_bf16(a, bw, gacc[t]);
        }
    }
#pragma unroll
    for (int t = 0; t < 5; t++) {
        int col = t * 16 + l16;
        float b2v = (col < 71) ? b2[col] : 0.f;
#pragma unroll
        for (int r = 0; r < 4; r++)
            sacc[t][r] = sacc[t][r] + gacc[t][r] + b2v;
    }

    bool valid4 = (l16 < 7);
#pragma unroll
    for (int r = 0; r < 4; r++) {
        float mx = -1e30f;
#pragma unroll
        for (int t = 0; t < 5; t++) {
            float v = sacc[t][r];
            if (t == 4 && !valid4) v = -1e30f;
            mx = fmaxf(mx, v);
        }
#pragma unroll
        for (int off = 1; off < 16; off <<= 1) mx = fmaxf(mx, __shfl_xor(mx, off, 16));
        float sum = 0.f;
#pragma unroll
        for (int t = 0; t < 5; t++) {
            float e = (t == 4 && !valid4) ? 0.f : __expf(sacc[t][r] - mx);
            sacc[t][r] = e;
            sum += e;
        }
#pragma unroll
        for (int off = 1; off < 16; off <<= 1) sum += __shfl_xor(sum, off, 16);
        float inv = 1.0f / sum;
#pragma unroll
        for (int t = 0; t < 5; t++) sacc[t][r] *= inv;
    }
#pragma unroll
    for (int t = 0; t < 5; t++) {
#pragma unroll
        for (int r = 0; r < 4; r++) {
            int row = wave * 16 + quad * 4 + r, col = t * 16 + l16;
            Sb[row * 104 + col] = f2bf(sacc[t][r]);
        }
    }
    __syncthreads();

    f32x4 oacc[4];
#pragma unroll
    for (int t = 0; t < 4; t++) oacc[t] = (f32x4){0.f, 0.f, 0.f, 0.f};
#pragma unroll
    for (int kk = 0; kk < 3; kk++) {
        short8 a = *(const short8*)&Sb[(wave * 16 + l16) * 104 + kk * 32 + quad * 8];
#pragma unroll
        for (int t = 0; t < 4; t++) {
            short8 bvv = *(const short8*)&VTs[(t * 16 + l16) * 104 + kk * 32 + quad * 8];
            oacc[t] = mfma_bf16(a, bvv, oacc[t]);
        }
    }
#pragma unroll
    for (int r = 0; r < 4; r++) {
        int l = wave * 16 + quad * 4 + r;
        if (l < 71) {
#pragma unroll
            for (int t = 0; t < 4; t++) {
                int col = hs + t * 16 + l16;
                if (MODE == 1)
                    AT[(size_t)(b * 71 + l) * 512 + col] = f2bf(oacc[t][r]);
                else
                    X2[(size_t)(b * 71 + l) * 512 + col] = oacc[t][r];
            }
        }
    }
}

// ---------------------------------------------------------------------------
// Output projection: 1136 blocks of 128x128, bijective XCD swizzle,
// 8 waves x 32x64, even/odd register double-buffer.
// ---------------------------------------------------------------------------
__global__ __launch_bounds__(512) void gemm_o_bf16_v2(
    const unsigned short* __restrict__ WoT,
    const float* __restrict__ bo,
    const unsigned short* __restrict__ AT,
    float* __restrict__ Y)
{
    const int tid  = threadIdx.x;
    const int wave = tid >> 6, lane = tid & 63;
    const int quad = lane >> 4, l16 = lane & 15;
    const int g   = blockIdx.x;
    const int wg  = (g & 7) * 142 + (g >> 3);
    const int m0  = (wg >> 2) * 128;
    const int n0  = (wg & 3) * 128;
    const int wm  = (wave >> 1) * 32, wn = (wave & 1) * 64;

    f32x4 acc[2][4];
#pragma unroll
    for (int i = 0; i < 2; i++)
#pragma unroll
        for (int j = 0; j < 4; j++) acc[i][j] = (f32x4){0.f, 0.f, 0.f, 0.f};

#define LDA(kk,i) (*(const short8*)&AT[(size_t)(m0 + wm + (i) * 16 + l16) * 512 + (kk) * 32 + quad * 8])
#define LDB(kk,j) (*(const short8*)&WoT[(size_t)(n0 + wn + (j) * 16 + l16) * 512 + (kk) * 32 + quad * 8])

    short8 aE[2], bE[4], aO[2], bO[4];
#pragma unroll
    for (int i = 0; i < 2; i++) aE[i] = LDA(0, i);
#pragma unroll
    for (int j = 0; j < 4; j++) bE[j] = LDB(0, j);

#pragma unroll
    for (int kp = 0; kp < 8; ++kp) {
        const int ko = 2 * kp + 1;
#pragma unroll
        for (int i = 0; i < 2; i++) aO[i] = LDA(ko, i);
#pragma unroll
        for (int j = 0; j < 4; j++) bO[j] = LDB(ko, j);
#pragma unroll
        for (int i = 0; i < 2; i++)
#pragma unroll
            for (int j = 0; j < 4; j++)
                acc[i][j] = mfma_bf16(aE[i], bE[j], acc[i][j]);
        if (kp < 7) {
            const int ke = 2 * kp + 2;
#pragma unroll
            for (int i = 0; i < 2; i++) aE[i] = LDA(ke, i);
#pragma unroll
            for (int j = 0; j < 4; j++) bE[j] = LDB(ke, j);
        }
#pragma unroll
        for (int i = 0; i < 2; i++)
#pragma unroll
            for (int j = 0; j < 4; j++)
                acc[i][j] = mfma_bf16(aO[i], bO[j], acc[i][j]);
    }
#undef LDA
#undef LDB

#pragma unroll
    for (int j = 0; j < 4; j++) {
        int gcol = n0 + wn + j * 16 + l16;
        float bvf = bo[gcol];
#pragma unroll
        for (int i = 0; i < 2; i++) {
#pragma unroll
            for (int r = 0; r < 4; r++) {
                int grow = m0 + wm + i * 16 + quad * 4 + r;
                Y[(size_t)grow * 512 + gcol] = acc[i][j][r] + bvf;
            }
        }
    }
}

// Fallback in-place O-projection. WMODE 0: bf16 WoT. WMODE 1: fp32 Wo gather.
template<int WMODE>
__global__ __launch_bounds__(512, 2) void gemm_o_inplace(
    const void* __restrict__ Wo_,
    const float* __restrict__ bo,
    float* __restrict__ Y)
{
    const int tid  = threadIdx.x;
    const int wave = tid >> 6, lane = tid & 63;
    const int quad = lane >> 4, l16 = lane & 15;
    const int m0 = blockIdx.x * 128;
    const int wm = (wave >> 2) * 64, wn = (wave & 3) * 128;

    f32x4 acc[4][8];
#pragma unroll
    for (int i = 0; i < 4; i++)
#pragma unroll
        for (int j = 0; j < 8; j++) acc[i][j] = (f32x4){0.f, 0.f, 0.f, 0.f};

    for (int kk = 0; kk < 16; ++kk) {
        const int k0 = kk * 32 + quad * 8;
        short8 af[4];
#pragma unroll
        for (int i = 0; i < 4; i++) {
            const float* p = Y + (size_t)(m0 + wm + i * 16 + l16) * 512 + k0;
            short8 a;
#pragma unroll
            for (int j = 0; j < 8; j++) a[j] = (short)f2bf(p[j]);
            af[i] = a;
        }
        short8 bfr[8];
#pragma unroll
        for (int j = 0; j < 8; j++) {
            if (WMODE == 1) {
                const float* wp = (const float*)Wo_ + (size_t)k0 * 512 + wn + j * 16 + l16;
                short8 bw;
#pragma unroll
                for (int e = 0; e < 8; e++) bw[e] = (short)f2bf(wp[(size_t)e * 512]);
                bfr[j] = bw;
            } else {
                bfr[j] = *(const short8*)&((const unsigned short*)Wo_)[(size_t)(wn + j * 16 + l16) * 512 + k0];
            }
        }
#pragma unroll
        for (int i = 0; i < 4; i++)
#pragma unroll
            for (int j = 0; j < 8; j++)
                acc[i][j] = mfma_bf16(af[i], bfr[j], acc[i][j]);
    }

    __syncthreads();

#pragma unroll
    for (int j = 0; j < 8; j++) {
        int gcol = wn + j * 16 + l16;
        float bvf = bo[gcol];
#pragma unroll
        for (int i = 0; i < 4; i++) {
#pragma unroll
            for (int r = 0; r < 4; r++) {
                int grow = m0 + wm + i * 16 + quad * 4 + r;
                Y[(size_t)grow * 512 + gcol] = acc[i][j][r] + bvf;
            }
        }
    }
}

extern "C" void kernel_launch(void* const* d_in, const int* in_sizes, int n_in,
                              void* d_out, int out_size, void* d_ws, size_t ws_size,
                              hipStream_t stream) {
    (void)in_sizes; (void)n_in; (void)out_size;
    const float* query = (const float*)d_in[0];
    const float* key_  = (const float*)d_in[1];
    const float* value = (const float*)d_in[2];
    const float* Wq = (const float*)d_in[3];
    const float* bq = (const float*)d_in[4];
    const float* Wk = (const float*)d_in[5];
    const float* bk = (const float*)d_in[6];
    const float* Wv = (const float*)d_in[7];
    const float* bv = (const float*)d_in[8];
    const float* Wo = (const float*)d_in[9];
    const float* bo = (const float*)d_in[10];
    const float* w1 = (const float*)d_in[11];
    const float* b1 = (const float*)d_in[12];
    const float* w2 = (const float*)d_in[13];
    const float* b2 = (const float*)d_in[14];

    unsigned short* wsT = (unsigned short*)d_ws;
    unsigned short* WqT = wsT;
    unsigned short* WkT = wsT + 262144;
    unsigned short* WvT = wsT + 524288;
    unsigned short* WoT = wsT + 786432;
    unsigned short* w1T = wsT + WS_W1T_OFF;
    unsigned short* w2T = wsT + WS_W2T_OFF;
    unsigned short* AT  = wsT + WS_AT_OFF;
    unsigned short* Qp  = wsT + WS_QP_OFF;
    unsigned short* Kp  = wsT + WS_KP_OFF;
    unsigned short* Vp  = wsT + WS_VP_OFF;
    const size_t NEED_W    = (size_t)WS_AT_OFF * 2;                          // ~2.1 MB
    const size_t NEED_BIG  = ((size_t)WS_AT_OFF + (size_t)MM * 512) * 2;     // ~39.4 MB
    const size_t NEED_FULL = ((size_t)WS_AT_OFF + 4 * (size_t)MM * 512) * 2; // ~151 MB

    float* X2 = (float*)d_out;

    if (d_ws == nullptr || ws_size < NEED_W) {
        // LEGACY path (verified baseline): zero workspace bytes used.
        attn_fused<2><<<4096, 320, 0, stream>>>(query, key_, value,
                                                Wq, bq, Wk, bk, Wv, bv,
                                                w1, b1, w2, b2, X2, nullptr);
        gemm_o_inplace<1><<<284, 512, 0, stream>>>(Wo, bo, X2);
        return;
    }

    wcvt512<<<256, 256, 0, stream>>>(Wq, Wk, Wv, Wo, WqT, WkT, WvT, WoT);
    sfcvt<<<1, 256, 0, stream>>>(w1, w2, w1T, w2T);

    if (ws_size >= NEED_FULL) {
        qkv_gemm<<<3408, 512, 0, stream>>>(query, key_, value,
                                           WqT, WkT, WvT, bq, bk, bv,
                                           Qp, Kp, Vp);
        attn2<<<4096, 320, 0, stream>>>(Qp, Kp, Vp, w1T, b1, w2T, b2, AT);
        gemm_o_bf16_v2<<<1136, 512, 0, stream>>>(WoT, bo, AT, X2);
    } else if (ws_size >= NEED_BIG) {
        attn_fused<1><<<4096, 320, 0, stream>>>(query, key_, value,
                                                WqT, bq, WkT, bk, WvT, bv,
                                                w1T, b1, w2T, b2, nullptr, AT);
        gemm_o_bf16_v2<<<1136, 512, 0, stream>>>(WoT, bo, AT, X2);
    } else {
        attn_fused<0><<<4096, 320, 0, stream>>>(query, key_, value,
                                                WqT, bq, WkT, bk, WvT, bv,
                                                w1T, b1, w2T, b2, X2, nullptr);
        gemm_o_inplace<0><<<284, 512, 0, stream>>>(WoT, bo, X2);
    }
}

// Round 6
// 561.480 us; speedup vs baseline: 2.0858x; 1.5981x over previous
//
#include <hip/hip_runtime.h>
#include <math.h>

#define Bb 512
#define Ll 71
#define Dd 512
#define Hh 8
#define DH 64
#define MM (Bb*Ll)   // 36352 = 284 * 128

typedef __attribute__((ext_vector_type(8))) short short8;
typedef __attribute__((ext_vector_type(4))) float f32x4;

static __device__ __forceinline__ f32x4 mfma_bf16(short8 a, short8 b, f32x4 c) {
    return __builtin_amdgcn_mfma_f32_16x16x32_bf16(a, b, c, 0, 0, 0);
}

// fp32 -> bf16 with round-to-nearest-even
static __device__ __forceinline__ unsigned short f2bf(float f) {
    union { float f; unsigned u; } v; v.f = f;
    unsigned r = v.u + 0x7FFFu + ((v.u >> 16) & 1u);
    return (unsigned short)(r >> 16);
}

// ---------------------------------------------------------------------------
// ws layout (ushort elements):
//   0        WqT  bf16 [512 n][512 k]
//   262144   WkT  bf16 [512][512]
//   524288   WvT  bf16 [512][512]
//   786432   WoT  bf16 [512][512]
//   1048576  w1T  bf16 [128 n][96 k]   (k >= 71 zeroed)
//   1060864  w2T  bf16 [80 n][128 k]   (n >= 71 rows zeroed)
//   1071104  AT   bf16 [36352][512]    (attention output)
//   19683328 Qp   bf16 [36352][512]    (projected Q, bias added)
//   38295552 Kp   bf16 [36352][512]
//   56907776 Vp   bf16 [36352][512]
// ---------------------------------------------------------------------------
#define WS_W1T_OFF 1048576
#define WS_W2T_OFF 1060864
#define WS_AT_OFF  1071104
#define WS_QP_OFF  19683328
#define WS_KP_OFF  38295552
#define WS_VP_OFF  56907776

// Transpose+convert one 64x64 tile of a 512x512 fp32 weight into bf16 [n][k].
__global__ __launch_bounds__(256) void wcvt512(
    const float* __restrict__ W0, const float* __restrict__ W1,
    const float* __restrict__ W2, const float* __restrict__ W3,
    unsigned short* __restrict__ T0, unsigned short* __restrict__ T1,
    unsigned short* __restrict__ T2, unsigned short* __restrict__ T3)
{
    __shared__ unsigned short t[64][72];
    const int m    = blockIdx.x >> 6;
    const int tile = blockIdx.x & 63;
    const float* W = (m == 0) ? W0 : (m == 1) ? W1 : (m == 2) ? W2 : W3;
    unsigned short* T = (m == 0) ? T0 : (m == 1) ? T1 : (m == 2) ? T2 : T3;
    const int tk = (tile >> 3) * 64, tn = (tile & 7) * 64;
    const int ln = threadIdx.x & 63, lr = threadIdx.x >> 6;
#pragma unroll
    for (int r = lr; r < 64; r += 4)
        t[ln][r] = f2bf(W[(size_t)(tk + r) * 512 + tn + ln]);
    __syncthreads();
#pragma unroll
    for (int r = lr; r < 64; r += 4)
        T[(size_t)(tn + r) * 512 + tk + ln] = t[r][ln];
}

// Convert w1 [71][128] -> w1T [128][96] (k>=71 zero) and
//         w2 [128][71] -> w2T [80][128] (n>=71 rows zero).
__global__ __launch_bounds__(256) void sfcvt(
    const float* __restrict__ w1, const float* __restrict__ w2,
    unsigned short* __restrict__ w1T, unsigned short* __restrict__ w2T)
{
    const int tid = threadIdx.x;
    for (int i = tid; i < 128 * 96; i += 256) {
        int n = i / 96, k = i % 96;
        w1T[i] = (k < 71) ? f2bf(w1[(size_t)k * 128 + n]) : (unsigned short)0;
    }
    for (int i = tid; i < 80 * 128; i += 256) {
        int n = i / 128, k = i % 128;
        w2T[i] = (n < 71) ? f2bf(w2[(size_t)k * 71 + n]) : (unsigned short)0;
    }
}

// ---------------------------------------------------------------------------
// QKV projection GEMM v3 (LDS-staged, m97-style): 128x128 tile, BK=64,
// 512 thr = 8 waves x (32x64), double-buffered XOR-swizzled LDS, async
// staging (loads issued before compute, ds_write after). A = fp32 X with
// f2bf at stage time; B = bf16 WT [n][k]. 3408 blocks, bijective XCD swz.
// ---------------------------------------------------------------------------
__global__ __launch_bounds__(512) void qkv_gemm_v3(
    const float* __restrict__ X0, const float* __restrict__ X1,
    const float* __restrict__ X2i,
    const unsigned short* __restrict__ W0T,
    const unsigned short* __restrict__ W1T,
    const unsigned short* __restrict__ W2T,
    const float* __restrict__ bb0, const float* __restrict__ bb1,
    const float* __restrict__ bb2,
    unsigned short* __restrict__ O0, unsigned short* __restrict__ O1,
    unsigned short* __restrict__ O2)
{
    __shared__ unsigned short As[2][8192];   // [128][64] bf16, swizzled
    __shared__ unsigned short Bs[2][8192];

    const int tid  = threadIdx.x;
    const int wave = tid >> 6, lane = tid & 63;
    const int quad = lane >> 4, l16 = lane & 15;
    // bijective XCD swizzle: 3408 = 8 * 426
    const int g   = blockIdx.x;
    const int wg  = (g & 7) * 426 + (g >> 3);
    const int mat = wg / 1136;
    const int r_  = wg - mat * 1136;
    const int m0  = (r_ >> 2) * 128, n0 = (r_ & 3) * 128;
    const float* X = (mat == 0) ? X0 : (mat == 1) ? X1 : X2i;
    const unsigned short* WT = (mat == 0) ? W0T : (mat == 1) ? W1T : W2T;
    const float* bias = (mat == 0) ? bb0 : (mat == 1) ? bb1 : bb2;
    unsigned short* O = (mat == 0) ? O0 : (mat == 1) ? O1 : O2;

    const int wm = (wave >> 1) * 32, wn = (wave & 1) * 64;

    // staging: thread -> row sr (0..127), quarter sq (0..3) = 16 elems
    const int sr = tid >> 2, sq = tid & 3;
    const float* aglob = X + (size_t)(m0 + sr) * 512 + sq * 16;
    const unsigned short* bglob = WT + (size_t)(n0 + sr) * 512 + sq * 16;
    const int aw0 = sr * 64 + (((sq * 2 + 0) ^ (sr & 7)) << 3);
    const int aw1 = sr * 64 + (((sq * 2 + 1) ^ (sr & 7)) << 3);

    f32x4 acc[2][4];
#pragma unroll
    for (int i = 0; i < 2; i++)
#pragma unroll
        for (int j = 0; j < 4; j++) acc[i][j] = (f32x4){0.f, 0.f, 0.f, 0.f};

    // ---- prologue: stage kt=0 into buf 0
    {
        f32x4 av[4];
#pragma unroll
        for (int p = 0; p < 4; p++) av[p] = *(const f32x4*)(aglob + p * 4);
        short8 bv0 = *(const short8*)bglob;
        short8 bv1 = *(const short8*)(bglob + 8);
        short8 s0, s1;
#pragma unroll
        for (int e = 0; e < 8; e++) {
            s0[e] = (short)f2bf(av[e >> 2][e & 3]);
            s1[e] = (short)f2bf(av[2 + (e >> 2)][e & 3]);
        }
        *(short8*)&As[0][aw0] = s0;
        *(short8*)&As[0][aw1] = s1;
        *(short8*)&Bs[0][aw0] = bv0;
        *(short8*)&Bs[0][aw1] = bv1;
    }
    __syncthreads();

#pragma unroll
    for (int kt = 0; kt < 8; ++kt) {
        const int cur = kt & 1;
        f32x4 av[4];
        short8 bv0, bv1;
        if (kt < 7) {    // issue next-tile loads early (latency hides under MFMA)
            const float* ag = aglob + (kt + 1) * 64;
            const unsigned short* bg = bglob + (kt + 1) * 64;
#pragma unroll
            for (int p = 0; p < 4; p++) av[p] = *(const f32x4*)(ag + p * 4);
            bv0 = *(const short8*)bg;
            bv1 = *(const short8*)(bg + 8);
        }
        // compute current buffer
#pragma unroll
        for (int ks = 0; ks < 2; ++ks) {
            const int phys = (((ks * 4 + quad) ^ (l16 & 7)) << 3);
            short8 af[2], bf_[4];
#pragma unroll
            for (int i = 0; i < 2; i++)
                af[i] = *(const short8*)&As[cur][(wm + i * 16 + l16) * 64 + phys];
#pragma unroll
            for (int j = 0; j < 4; j++)
                bf_[j] = *(const short8*)&Bs[cur][(wn + j * 16 + l16) * 64 + phys];
#pragma unroll
            for (int i = 0; i < 2; i++)
#pragma unroll
                for (int j = 0; j < 4; j++)
                    acc[i][j] = mfma_bf16(af[i], bf_[j], acc[i][j]);
        }
        if (kt < 7) {    // convert + write next buffer
            short8 s0, s1;
#pragma unroll
            for (int e = 0; e < 8; e++) {
                s0[e] = (short)f2bf(av[e >> 2][e & 3]);
                s1[e] = (short)f2bf(av[2 + (e >> 2)][e & 3]);
            }
            const int nxt = cur ^ 1;
            *(short8*)&As[nxt][aw0] = s0;
            *(short8*)&As[nxt][aw1] = s1;
            *(short8*)&Bs[nxt][aw0] = bv0;
            *(short8*)&Bs[nxt][aw1] = bv1;
        }
        __syncthreads();
    }

#pragma unroll
    for (int j = 0; j < 4; j++) {
        const int gcol = n0 + wn + j * 16 + l16;
        const float bvf = bias[gcol];
#pragma unroll
        for (int i = 0; i < 2; i++) {
#pragma unroll
            for (int r = 0; r < 4; r++) {
                const int grow = m0 + wm + i * 16 + quad * 4 + r;
                O[(size_t)grow * 512 + gcol] = f2bf(acc[i][j][r] + bvf);
            }
        }
    }
}

// ---------------------------------------------------------------------------
// Output projection GEMM v3: same LDS-staged structure, A = bf16 AT,
// B = bf16 WoT, fp32 output + bias. 1136 blocks, bijective XCD swizzle.
// ---------------------------------------------------------------------------
__global__ __launch_bounds__(512) void gemm_o_v3(
    const unsigned short* __restrict__ WoT,  // [512 n][512 k] bf16
    const float* __restrict__ bo,
    const unsigned short* __restrict__ AT,   // [36352][512] bf16
    float* __restrict__ Y)                   // [36352][512] fp32
{
    __shared__ unsigned short As[2][8192];
    __shared__ unsigned short Bs[2][8192];

    const int tid  = threadIdx.x;
    const int wave = tid >> 6, lane = tid & 63;
    const int quad = lane >> 4, l16 = lane & 15;
    const int g   = blockIdx.x;
    const int wg  = (g & 7) * 142 + (g >> 3);   // 1136 = 8*142
    const int m0  = (wg >> 2) * 128, n0 = (wg & 3) * 128;
    const int wm = (wave >> 1) * 32, wn = (wave & 1) * 64;

    const int sr = tid >> 2, sq = tid & 3;
    const unsigned short* aglob = AT + (size_t)(m0 + sr) * 512 + sq * 16;
    const unsigned short* bglob = WoT + (size_t)(n0 + sr) * 512 + sq * 16;
    const int aw0 = sr * 64 + (((sq * 2 + 0) ^ (sr & 7)) << 3);
    const int aw1 = sr * 64 + (((sq * 2 + 1) ^ (sr & 7)) << 3);

    f32x4 acc[2][4];
#pragma unroll
    for (int i = 0; i < 2; i++)
#pragma unroll
        for (int j = 0; j < 4; j++) acc[i][j] = (f32x4){0.f, 0.f, 0.f, 0.f};

    {
        short8 a0 = *(const short8*)aglob;
        short8 a1 = *(const short8*)(aglob + 8);
        short8 b0 = *(const short8*)bglob;
        short8 b1 = *(const short8*)(bglob + 8);
        *(short8*)&As[0][aw0] = a0;
        *(short8*)&As[0][aw1] = a1;
        *(short8*)&Bs[0][aw0] = b0;
        *(short8*)&Bs[0][aw1] = b1;
    }
    __syncthreads();

#pragma unroll
    for (int kt = 0; kt < 8; ++kt) {
        const int cur = kt & 1;
        short8 a0, a1, b0, b1;
        if (kt < 7) {
            const unsigned short* ag = aglob + (kt + 1) * 64;
            const unsigned short* bg = bglob + (kt + 1) * 64;
            a0 = *(const short8*)ag;  a1 = *(const short8*)(ag + 8);
            b0 = *(const short8*)bg;  b1 = *(const short8*)(bg + 8);
        }
#pragma unroll
        for (int ks = 0; ks < 2; ++ks) {
            const int phys = (((ks * 4 + quad) ^ (l16 & 7)) << 3);
            short8 af[2], bf_[4];
#pragma unroll
            for (int i = 0; i < 2; i++)
                af[i] = *(const short8*)&As[cur][(wm + i * 16 + l16) * 64 + phys];
#pragma unroll
            for (int j = 0; j < 4; j++)
                bf_[j] = *(const short8*)&Bs[cur][(wn + j * 16 + l16) * 64 + phys];
#pragma unroll
            for (int i = 0; i < 2; i++)
#pragma unroll
                for (int j = 0; j < 4; j++)
                    acc[i][j] = mfma_bf16(af[i], bf_[j], acc[i][j]);
        }
        if (kt < 7) {
            const int nxt = cur ^ 1;
            *(short8*)&As[nxt][aw0] = a0;
            *(short8*)&As[nxt][aw1] = a1;
            *(short8*)&Bs[nxt][aw0] = b0;
            *(short8*)&Bs[nxt][aw1] = b1;
        }
        __syncthreads();
    }

#pragma unroll
    for (int j = 0; j < 4; j++) {
        const int gcol = n0 + wn + j * 16 + l16;
        const float bvf = bo[gcol];
#pragma unroll
        for (int i = 0; i < 2; i++) {
#pragma unroll
            for (int r = 0; r < 4; r++) {
                const int grow = m0 + wm + i * 16 + quad * 4 + r;
                Y[(size_t)grow * 512 + gcol] = acc[i][j][r] + bvf;
            }
        }
    }
}

// ---------------------------------------------------------------------------
// Attention-only kernel per (b,h). 320 thr = 5 waves. (unchanged, verified)
// ---------------------------------------------------------------------------
__global__ __launch_bounds__(320) void attn2(
    const unsigned short* __restrict__ Qp,
    const unsigned short* __restrict__ Kp,
    const unsigned short* __restrict__ Vp,
    const unsigned short* __restrict__ w1T,  // [128][96] bf16
    const float* __restrict__ b1,            // [128]
    const unsigned short* __restrict__ w2T,  // [80][128] bf16
    const float* __restrict__ b2,            // [71]
    unsigned short* __restrict__ AT)         // [36352][512] bf16
{
    __shared__ __align__(16) unsigned short smem[25856];
    unsigned short* VTs = smem;              // [64][104]  V^T, k-contig
    unsigned short* Sb  = smem + 6656;       // [80][104]
    unsigned short* H1s = smem + 14976;      // [80][136]

    const int tid = threadIdx.x;
    const int wave = tid >> 6, lane = tid & 63;
    const int quad = lane >> 4, l16 = lane & 15;
    const int x = blockIdx.x;
    const int b = ((x >> 6) << 3) | (x & 7);   // XCD-aware remap
    const int h = (x >> 3) & 7;
    const int hs = h * 64;
    const unsigned short* Qr = Qp + (size_t)(b * 71) * 512 + hs;
    const unsigned short* Kr = Kp + (size_t)(b * 71) * 512 + hs;
    const unsigned short* Vr = Vp + (size_t)(b * 71) * 512 + hs;

    // zero pads
    for (int i = tid; i < 1600; i += 320) {   // VTs k-cols [71,96) all n
        int n = i / 25, c = 71 + (i % 25);
        VTs[n * 104 + c] = 0;
    }
    for (int i = tid; i < 1280; i += 320) {   // Sb cols [80,96)
        int r = i >> 4, c = 80 + (i & 15);
        Sb[r * 104 + c] = 0;
    }
    // V scatter -> VTs[col][row]
    for (int i = tid; i < 568; i += 320) {
        int row = i >> 3, c8 = i & 7;
        short8 v = *(const short8*)&Vr[(size_t)row * 512 + c8 * 8];
#pragma unroll
        for (int e = 0; e < 8; e++)
            VTs[(c8 * 8 + e) * 104 + row] = (unsigned short)v[e];
    }
    __syncthreads();

    // ---- phase 1: scores = Q K^T / 8, Q/K frags direct from global
    f32x4 sacc[5];
#pragma unroll
    for (int t = 0; t < 5; t++) sacc[t] = (f32x4){0.f, 0.f, 0.f, 0.f};
    const int arow = wave * 16 + l16;
    const bool aok = (arow < 71);
#pragma unroll
    for (int kk = 0; kk < 2; kk++) {
        short8 aq = aok ? *(const short8*)&Qr[(size_t)arow * 512 + kk * 32 + quad * 8]
                        : (short8){0,0,0,0,0,0,0,0};
#pragma unroll
        for (int t = 0; t < 5; t++) {
            const int brow = t * 16 + l16;
            short8 bk_ = (brow < 71)
                ? *(const short8*)&Kr[(size_t)brow * 512 + kk * 32 + quad * 8]
                : (short8){0,0,0,0,0,0,0,0};
            sacc[t] = mfma_bf16(aq, bk_, sacc[t]);
        }
    }
#pragma unroll
    for (int t = 0; t < 5; t++) {
#pragma unroll
        for (int r = 0; r < 4; r++) {
            sacc[t][r] *= 0.125f;
            int row = wave * 16 + quad * 4 + r, col = t * 16 + l16;
            Sb[row * 104 + col] = f2bf(sacc[t][r]);
        }
    }
    __syncthreads();

    // ---- phase 2: H1 = gelu(S @ W1 + b1)
    f32x4 hacc[8];
#pragma unroll
    for (int t = 0; t < 8; t++) hacc[t] = (f32x4){0.f, 0.f, 0.f, 0.f};
#pragma unroll
    for (int kk = 0; kk < 3; kk++) {
        short8 a = *(const short8*)&Sb[(wave * 16 + l16) * 104 + kk * 32 + quad * 8];
        const int k0 = kk * 32 + quad * 8;
#pragma unroll
        for (int t = 0; t < 8; t++) {
            short8 bw = *(const short8*)&w1T[(size_t)(t * 16 + l16) * 96 + k0];
            hacc[t] = mfma_bf16(a, bw, hacc[t]);
        }
    }
#pragma unroll
    for (int t = 0; t < 8; t++) {
        int col = t * 16 + l16;
        float bvf = b1[col];
#pragma unroll
        for (int r = 0; r < 4; r++) {
            float z = hacc[t][r] + bvf;
            float g = 0.5f * z * (1.0f + erff(z * 0.70710678118654752f));
            int row = wave * 16 + quad * 4 + r;
            H1s[row * 136 + col] = f2bf(g);
        }
    }
    __syncthreads();

    // ---- phase 3: G = H1 @ W2
    f32x4 gacc[5];
#pragma unroll
    for (int t = 0; t < 5; t++) gacc[t] = (f32x4){0.f, 0.f, 0.f, 0.f};
#pragma unroll
    for (int kk = 0; kk < 4; kk++) {
        short8 a = *(const short8*)&H1s[(wave * 16 + l16) * 136 + kk * 32 + quad * 8];
        const int k0 = kk * 32 + quad * 8;
#pragma unroll
        for (int t = 0; t < 5; t++) {
            short8 bw = *(const short8*)&w2T[(size_t)(t * 16 + l16) * 128 + k0];
            gacc[t] = mfma_bf16(a, bw, gacc[t]);
        }
    }
#pragma unroll
    for (int t = 0; t < 5; t++) {
        int col = t * 16 + l16;
        float b2v = (col < 71) ? b2[col] : 0.f;
#pragma unroll
        for (int r = 0; r < 4; r++)
            sacc[t][r] = sacc[t][r] + gacc[t][r] + b2v;
    }

    // ---- phase 4: softmax over cols 0..70
    bool valid4 = (l16 < 7);
#pragma unroll
    for (int r = 0; r < 4; r++) {
        float mx = -1e30f;
#pragma unroll
        for (int t = 0; t < 5; t++) {
            float v = sacc[t][r];
            if (t == 4 && !valid4) v = -1e30f;
            mx = fmaxf(mx, v);
        }
#pragma unroll
        for (int off = 1; off < 16; off <<= 1) mx = fmaxf(mx, __shfl_xor(mx, off, 16));
        float sum = 0.f;
#pragma unroll
        for (int t = 0; t < 5; t++) {
            float e = (t == 4 && !valid4) ? 0.f : __expf(sacc[t][r] - mx);
            sacc[t][r] = e;
            sum += e;
        }
#pragma unroll
        for (int off = 1; off < 16; off <<= 1) sum += __shfl_xor(sum, off, 16);
        float inv = 1.0f / sum;
#pragma unroll
        for (int t = 0; t < 5; t++) sacc[t][r] *= inv;
    }
#pragma unroll
    for (int t = 0; t < 5; t++) {
#pragma unroll
        for (int r = 0; r < 4; r++) {
            int row = wave * 16 + quad * 4 + r, col = t * 16 + l16;
            Sb[row * 104 + col] = f2bf(sacc[t][r]);   // P; cols 71..95 exact 0
        }
    }
    __syncthreads();

    // ---- phase 5: O = P @ V -> AT bf16
    f32x4 oacc[4];
#pragma unroll
    for (int t = 0; t < 4; t++) oacc[t] = (f32x4){0.f, 0.f, 0.f, 0.f};
#pragma unroll
    for (int kk = 0; kk < 3; kk++) {
        short8 a = *(const short8*)&Sb[(wave * 16 + l16) * 104 + kk * 32 + quad * 8];
#pragma unroll
        for (int t = 0; t < 4; t++) {
            short8 bvv = *(const short8*)&VTs[(t * 16 + l16) * 104 + kk * 32 + quad * 8];
            oacc[t] = mfma_bf16(a, bvv, oacc[t]);
        }
    }
#pragma unroll
    for (int r = 0; r < 4; r++) {
        int l = wave * 16 + quad * 4 + r;
        if (l < 71) {
#pragma unroll
            for (int t = 0; t < 4; t++)
                AT[(size_t)(b * 71 + l) * 512 + hs + t * 16 + l16] = f2bf(oacc[t][r]);
        }
    }
}

// ---------------------------------------------------------------------------
// Fallback projection helpers + fused kernel (verified paths).
// ---------------------------------------------------------------------------
static __device__ __forceinline__ void proj_g(
    const float* __restrict__ Xrows,
    const unsigned short* __restrict__ WT,
    int hs, int wave, int quad, int l16, f32x4 acc[4])
{
    const int arow = wave * 16 + l16;
    const bool ok = (arow < 71);
    const float* ap = Xrows + (size_t)arow * 512 + quad * 8;
    const unsigned short* w0 = WT + (size_t)(hs + l16) * 512 + quad * 8;
#pragma unroll 4
    for (int kk = 0; kk < 16; ++kk) {
        short8 a;
        if (ok) {
            const f32x4 p0 = *(const f32x4*)(ap + (size_t)kk * 32);
            const f32x4 p1 = *(const f32x4*)(ap + (size_t)kk * 32 + 4);
#pragma unroll
            for (int j = 0; j < 4; j++) {
                a[j]     = (short)f2bf(p0[j]);
                a[4 + j] = (short)f2bf(p1[j]);
            }
        } else {
            a = (short8){0,0,0,0,0,0,0,0};
        }
#pragma unroll
        for (int t = 0; t < 4; t++) {
            short8 bw = *(const short8*)(w0 + (size_t)t * (16 * 512) + kk * 32);
            acc[t] = mfma_bf16(a, bw, acc[t]);
        }
    }
}

static __device__ __forceinline__ void proj_g_legacy(
    const float* __restrict__ Xrows,
    const float* __restrict__ W,
    int hs, int wave, int quad, int l16, f32x4 acc[4])
{
    const int arow = wave * 16 + l16;
    const bool ok = (arow < 71);
    const float* ap = Xrows + (size_t)arow * 512 + quad * 8;
    const int nb = hs + l16;
#pragma unroll 2
    for (int kk = 0; kk < 16; ++kk) {
        short8 a;
        if (ok) {
            const float* p = ap + (size_t)kk * 32;
#pragma unroll
            for (int j = 0; j < 8; j++) a[j] = (short)f2bf(p[j]);
        } else {
            a = (short8){0,0,0,0,0,0,0,0};
        }
        const int k0 = kk * 32 + quad * 8;
#pragma unroll
        for (int t = 0; t < 4; t++) {
            const float* wp = W + (size_t)k0 * 512 + nb + t * 16;
            short8 bw;
#pragma unroll
            for (int j = 0; j < 8; j++) bw[j] = (short)f2bf(wp[(size_t)j * 512]);
            acc[t] = mfma_bf16(a, bw, acc[t]);
        }
    }
}

// MODE 0: bf16 W, fp32 X, fp32 out.  MODE 1: bf16 W, fp32 X, bf16 out.
// MODE 2: legacy fp32 everything.
template<int MODE>
__global__ __launch_bounds__(320) void attn_fused(
    const float* __restrict__ query,
    const float* __restrict__ key_,
    const float* __restrict__ value,
    const void* __restrict__ Wq_, const float* __restrict__ bq,
    const void* __restrict__ Wk_, const float* __restrict__ bk,
    const void* __restrict__ Wv_, const float* __restrict__ bv,
    const void* __restrict__ w1_,
    const float* __restrict__ b1,
    const void* __restrict__ w2_,
    const float* __restrict__ b2,
    float* __restrict__ X2,
    unsigned short* __restrict__ AT)
{
    __shared__ __align__(16) unsigned short smem[26496];
    unsigned short* Qs  = smem;              // [80][72]
    unsigned short* Ks  = smem + 5760;       // [80][72]
    unsigned short* H1s = smem;              // [80][136] overlays Qs+Ks
    unsigned short* VTs = smem + 11520;      // [64][104]
    unsigned short* Sb  = smem + 18176;      // [80][104]

    const int tid = threadIdx.x;
    const int wave = tid >> 6, lane = tid & 63;
    const int quad = lane >> 4, l16 = lane & 15;
    const int x = blockIdx.x;
    const int b = ((x >> 6) << 3) | (x & 7);
    const int h = (x >> 3) & 7;
    const int hs = h * 64;
    const float* Xq = query + (size_t)(b * 71) * 512;
    const float* Xk = key_  + (size_t)(b * 71) * 512;
    const float* Xv = value + (size_t)(b * 71) * 512;

    for (int i = tid; i < 1280; i += 320) {
        int r = i >> 4, c = 80 + (i & 15);
        Sb[r * 104 + c] = 0;
    }
    for (int i = tid; i < 1024; i += 320) {
        int n = i >> 4, c = 80 + (i & 15);
        VTs[n * 104 + c] = 0;
    }

    {
        f32x4 acc[4];
#pragma unroll
        for (int t = 0; t < 4; t++) acc[t] = (f32x4){0.f, 0.f, 0.f, 0.f};
        if (MODE == 2) proj_g_legacy(Xq, (const float*)Wq_, hs, wave, quad, l16, acc);
        else           proj_g(Xq, (const unsigned short*)Wq_, hs, wave, quad, l16, acc);
#pragma unroll
        for (int t = 0; t < 4; t++) {
            int col = t * 16 + l16;
            float bb = bq[hs + col];
#pragma unroll
            for (int r = 0; r < 4; r++) {
                int row = wave * 16 + quad * 4 + r;
                Qs[row * 72 + col] = f2bf(acc[t][r] + bb);
            }
        }
    }
    {
        f32x4 acc[4];
#pragma unroll
        for (int t = 0; t < 4; t++) acc[t] = (f32x4){0.f, 0.f, 0.f, 0.f};
        if (MODE == 2) proj_g_legacy(Xk, (const float*)Wk_, hs, wave, quad, l16, acc);
        else           proj_g(Xk, (const unsigned short*)Wk_, hs, wave, quad, l16, acc);
#pragma unroll
        for (int t = 0; t < 4; t++) {
            int col = t * 16 + l16;
            float bb = bk[hs + col];
#pragma unroll
            for (int r = 0; r < 4; r++) {
                int row = wave * 16 + quad * 4 + r;
                Ks[row * 72 + col] = f2bf(acc[t][r] + bb);
            }
        }
    }
    {
        f32x4 acc[4];
#pragma unroll
        for (int t = 0; t < 4; t++) acc[t] = (f32x4){0.f, 0.f, 0.f, 0.f};
        if (MODE == 2) proj_g_legacy(Xv, (const float*)Wv_, hs, wave, quad, l16, acc);
        else           proj_g(Xv, (const unsigned short*)Wv_, hs, wave, quad, l16, acc);
#pragma unroll
        for (int t = 0; t < 4; t++) {
            int col = t * 16 + l16;
            float bb = bv[hs + col];
#pragma unroll
            for (int r = 0; r < 4; r++) {
                int row = wave * 16 + quad * 4 + r;
                float v = (row < 71) ? (acc[t][r] + bb) : 0.f;
                VTs[col * 104 + row] = f2bf(v);
            }
        }
    }
    __syncthreads();

    f32x4 sacc[5];
#pragma unroll
    for (int t = 0; t < 5; t++) sacc[t] = (f32x4){0.f, 0.f, 0.f, 0.f};
#pragma unroll
    for (int kk = 0; kk < 2; kk++) {
        short8 aq = *(const short8*)&Qs[(wave * 16 + l16) * 72 + kk * 32 + quad * 8];
#pragma unroll
        for (int t = 0; t < 5; t++) {
            short8 bk_ = *(const short8*)&Ks[(t * 16 + l16) * 72 + kk * 32 + quad * 8];
            sacc[t] = mfma_bf16(aq, bk_, sacc[t]);
        }
    }
#pragma unroll
    for (int t = 0; t < 5; t++) {
#pragma unroll
        for (int r = 0; r < 4; r++) {
            sacc[t][r] *= 0.125f;
            int row = wave * 16 + quad * 4 + r, col = t * 16 + l16;
            Sb[row * 104 + col] = f2bf(sacc[t][r]);
        }
    }
    __syncthreads();

    f32x4 hacc[8];
#pragma unroll
    for (int t = 0; t < 8; t++) hacc[t] = (f32x4){0.f, 0.f, 0.f, 0.f};
#pragma unroll
    for (int kk = 0; kk < 3; kk++) {
        short8 a = *(const short8*)&Sb[(wave * 16 + l16) * 104 + kk * 32 + quad * 8];
        const int k0 = kk * 32 + quad * 8;
#pragma unroll
        for (int t = 0; t < 8; t++) {
            short8 bw;
            if (MODE == 2) {
                const float* wp = (const float*)w1_ + (size_t)k0 * 128 + t * 16 + l16;
#pragma unroll
                for (int j = 0; j < 8; j++)
                    bw[j] = (k0 + j < 71) ? (short)f2bf(wp[(size_t)j * 128]) : (short)0;
            } else {
                bw = *(const short8*)&((const unsigned short*)w1_)[(size_t)(t * 16 + l16) * 96 + k0];
            }
            hacc[t] = mfma_bf16(a, bw, hacc[t]);
        }
    }
#pragma unroll
    for (int t = 0; t < 8; t++) {
        int col = t * 16 + l16;
        float bvf = b1[col];
#pragma unroll
        for (int r = 0; r < 4; r++) {
            float z = hacc[t][r] + bvf;
            float g = 0.5f * z * (1.0f + erff(z * 0.70710678118654752f));
            int row = wave * 16 + quad * 4 + r;
            H1s[row * 136 + col] = f2bf(g);
        }
    }
    __syncthreads();

    f32x4 gacc[5];
#pragma unroll
    for (int t = 0; t < 5; t++) gacc[t] = (f32x4){0.f, 0.f, 0.f, 0.f};
#pragma unroll
    for (int kk = 0; kk < 4; kk++) {
        short8 a = *(const short8*)&H1s[(wave * 16 + l16) * 136 + kk * 32 + quad * 8];
        const int k0 = kk * 32 + quad * 8;
#pragma unroll
        for (int t = 0; t < 5; t++) {
            short8 bw;
            if (MODE == 2) {
                const int n = t * 16 + l16;
                const float* wp = (const float*)w2_ + (size_t)k0 * 71 + n;
#pragma unroll
                for (int j = 0; j < 8; j++)
                    bw[j] = (n < 71) ? (short)f2bf(wp[(size_t)j * 71]) : (short)0;
            } else {
                bw = *(const short8*)&((const unsigned short*)w2_)[(size_t)(t * 16 + l16) * 128 + k0];
            }
            gacc[t] = mfma_bf16(a, bw, gacc[t]);
        }
    }
#pragma unroll
    for (int t = 0; t < 5; t++) {
        int col = t * 16 + l16;
        float b2v = (col < 71) ? b2[col] : 0.f;
#pragma unroll
        for (int r = 0; r < 4; r++)
            sacc[t][r] = sacc[t][r] + gacc[t][r] + b2v;
    }

    bool valid4 = (l16 < 7);
#pragma unroll
    for (int r = 0; r < 4; r++) {
        float mx = -1e30f;
#pragma unroll
        for (int t = 0; t < 5; t++) {
            float v = sacc[t][r];
            if (t == 4 && !valid4) v = -1e30f;
            mx = fmaxf(mx, v);
        }
#pragma unroll
        for (int off = 1; off < 16; off <<= 1) mx = fmaxf(mx, __shfl_xor(mx, off, 16));
        float sum = 0.f;
#pragma unroll
        for (int t = 0; t < 5; t++) {
            float e = (t == 4 && !valid4) ? 0.f : __expf(sacc[t][r] - mx);
            sacc[t][r] = e;
            sum += e;
        }
#pragma unroll
        for (int off = 1; off < 16; off <<= 1) sum += __shfl_xor(sum, off, 16);
        float inv = 1.0f / sum;
#pragma unroll
        for (int t = 0; t < 5; t++) sacc[t][r] *= inv;
    }
#pragma unroll
    for (int t = 0; t < 5; t++) {
#pragma unroll
        for (int r = 0; r < 4; r++) {
            int row = wave * 16 + quad * 4 + r, col = t * 16 + l16;
            Sb[row * 104 + col] = f2bf(sacc[t][r]);
        }
    }
    __syncthreads();

    f32x4 oacc[4];
#pragma unroll
    for (int t = 0; t < 4; t++) oacc[t] = (f32x4){0.f, 0.f, 0.f, 0.f};
#pragma unroll
    for (int kk = 0; kk < 3; kk++) {
        short8 a = *(const short8*)&Sb[(wave * 16 + l16) * 104 + kk * 32 + quad * 8];
#pragma unroll
        for (int t = 0; t < 4; t++) {
            short8 bvv = *(const short8*)&VTs[(t * 16 + l16) * 104 + kk * 32 + quad * 8];
            oacc[t] = mfma_bf16(a, bvv, oacc[t]);
        }
    }
#pragma unroll
    for (int r = 0; r < 4; r++) {
        int l = wave * 16 + quad * 4 + r;
        if (l < 71) {
#pragma unroll
            for (int t = 0; t < 4; t++) {
                int col = hs + t * 16 + l16;
                if (MODE == 1)
                    AT[(size_t)(b * 71 + l) * 512 + col] = f2bf(oacc[t][r]);
                else
                    X2[(size_t)(b * 71 + l) * 512 + col] = oacc[t][r];
            }
        }
    }
}

// Fallback O-projection (NEED_BIG path): register double-buffer version.
__global__ __launch_bounds__(512) void gemm_o_bf16_v2(
    const unsigned short* __restrict__ WoT,
    const float* __restrict__ bo,
    const unsigned short* __restrict__ AT,
    float* __restrict__ Y)
{
    const int tid  = threadIdx.x;
    const int wave = tid >> 6, lane = tid & 63;
    const int quad = lane >> 4, l16 = lane & 15;
    const int g   = blockIdx.x;
    const int wg  = (g & 7) * 142 + (g >> 3);
    const int m0  = (wg >> 2) * 128;
    const int n0  = (wg & 3) * 128;
    const int wm  = (wave >> 1) * 32, wn = (wave & 1) * 64;

    f32x4 acc[2][4];
#pragma unroll
    for (int i = 0; i < 2; i++)
#pragma unroll
        for (int j = 0; j < 4; j++) acc[i][j] = (f32x4){0.f, 0.f, 0.f, 0.f};

#define LDA(kk,i) (*(const short8*)&AT[(size_t)(m0 + wm + (i) * 16 + l16) * 512 + (kk) * 32 + quad * 8])
#define LDB(kk,j) (*(const short8*)&WoT[(size_t)(n0 + wn + (j) * 16 + l16) * 512 + (kk) * 32 + quad * 8])

    short8 aE[2], bE[4], aO[2], bO[4];
#pragma unroll
    for (int i = 0; i < 2; i++) aE[i] = LDA(0, i);
#pragma unroll
    for (int j = 0; j < 4; j++) bE[j] = LDB(0, j);

#pragma unroll
    for (int kp = 0; kp < 8; ++kp) {
        const int ko = 2 * kp + 1;
#pragma unroll
        for (int i = 0; i < 2; i++) aO[i] = LDA(ko, i);
#pragma unroll
        for (int j = 0; j < 4; j++) bO[j] = LDB(ko, j);
#pragma unroll
        for (int i = 0; i < 2; i++)
#pragma unroll
            for (int j = 0; j < 4; j++)
                acc[i][j] = mfma_bf16(aE[i], bE[j], acc[i][j]);
        if (kp < 7) {
            const int ke = 2 * kp + 2;
#pragma unroll
            for (int i = 0; i < 2; i++) aE[i] = LDA(ke, i);
#pragma unroll
            for (int j = 0; j < 4; j++) bE[j] = LDB(ke, j);
        }
#pragma unroll
        for (int i = 0; i < 2; i++)
#pragma unroll
            for (int j = 0; j < 4; j++)
                acc[i][j] = mfma_bf16(aO[i], bO[j], acc[i][j]);
    }
#undef LDA
#undef LDB

#pragma unroll
    for (int j = 0; j < 4; j++) {
        int gcol = n0 + wn + j * 16 + l16;
        float bvf = bo[gcol];
#pragma unroll
        for (int i = 0; i < 2; i++) {
#pragma unroll
            for (int r = 0; r < 4; r++) {
                int grow = m0 + wm + i * 16 + quad * 4 + r;
                Y[(size_t)grow * 512 + gcol] = acc[i][j][r] + bvf;
            }
        }
    }
}

// Fallback in-place O-projection. WMODE 0: bf16 WoT. WMODE 1: fp32 Wo gather.
template<int WMODE>
__global__ __launch_bounds__(512, 2) void gemm_o_inplace(
    const void* __restrict__ Wo_,
    const float* __restrict__ bo,
    float* __restrict__ Y)
{
    const int tid  = threadIdx.x;
    const int wave = tid >> 6, lane = tid & 63;
    const int quad = lane >> 4, l16 = lane & 15;
    const int m0 = blockIdx.x * 128;
    const int wm = (wave >> 2) * 64, wn = (wave & 3) * 128;

    f32x4 acc[4][8];
#pragma unroll
    for (int i = 0; i < 4; i++)
#pragma unroll
        for (int j = 0; j < 8; j++) acc[i][j] = (f32x4){0.f, 0.f, 0.f, 0.f};

    for (int kk = 0; kk < 16; ++kk) {
        const int k0 = kk * 32 + quad * 8;
        short8 af[4];
#pragma unroll
        for (int i = 0; i < 4; i++) {
            const float* p = Y + (size_t)(m0 + wm + i * 16 + l16) * 512 + k0;
            short8 a;
#pragma unroll
            for (int j = 0; j < 8; j++) a[j] = (short)f2bf(p[j]);
            af[i] = a;
        }
        short8 bfr[8];
#pragma unroll
        for (int j = 0; j < 8; j++) {
            if (WMODE == 1) {
                const float* wp = (const float*)Wo_ + (size_t)k0 * 512 + wn + j * 16 + l16;
                short8 bw;
#pragma unroll
                for (int e = 0; e < 8; e++) bw[e] = (short)f2bf(wp[(size_t)e * 512]);
                bfr[j] = bw;
            } else {
                bfr[j] = *(const short8*)&((const unsigned short*)Wo_)[(size_t)(wn + j * 16 + l16) * 512 + k0];
            }
        }
#pragma unroll
        for (int i = 0; i < 4; i++)
#pragma unroll
            for (int j = 0; j < 8; j++)
                acc[i][j] = mfma_bf16(af[i], bfr[j], acc[i][j]);
    }

    __syncthreads();

#pragma unroll
    for (int j = 0; j < 8; j++) {
        int gcol = wn + j * 16 + l16;
        float bvf = bo[gcol];
#pragma unroll
        for (int i = 0; i < 4; i++) {
#pragma unroll
            for (int r = 0; r < 4; r++) {
                int grow = m0 + wm + i * 16 + quad * 4 + r;
                Y[(size_t)grow * 512 + gcol] = acc[i][j][r] + bvf;
            }
        }
    }
}

extern "C" void kernel_launch(void* const* d_in, const int* in_sizes, int n_in,
                              void* d_out, int out_size, void* d_ws, size_t ws_size,
                              hipStream_t stream) {
    (void)in_sizes; (void)n_in; (void)out_size;
    const float* query = (const float*)d_in[0];
    const float* key_  = (const float*)d_in[1];
    const float* value = (const float*)d_in[2];
    const float* Wq = (const float*)d_in[3];
    const float* bq = (const float*)d_in[4];
    const float* Wk = (const float*)d_in[5];
    const float* bk = (const float*)d_in[6];
    const float* Wv = (const float*)d_in[7];
    const float* bv = (const float*)d_in[8];
    const float* Wo = (const float*)d_in[9];
    const float* bo = (const float*)d_in[10];
    const float* w1 = (const float*)d_in[11];
    const float* b1 = (const float*)d_in[12];
    const float* w2 = (const float*)d_in[13];
    const float* b2 = (const float*)d_in[14];

    unsigned short* wsT = (unsigned short*)d_ws;
    unsigned short* WqT = wsT;
    unsigned short* WkT = wsT + 262144;
    unsigned short* WvT = wsT + 524288;
    unsigned short* WoT = wsT + 786432;
    unsigned short* w1T = wsT + WS_W1T_OFF;
    unsigned short* w2T = wsT + WS_W2T_OFF;
    unsigned short* AT  = wsT + WS_AT_OFF;
    unsigned short* Qp  = wsT + WS_QP_OFF;
    unsigned short* Kp  = wsT + WS_KP_OFF;
    unsigned short* Vp  = wsT + WS_VP_OFF;
    const size_t NEED_W    = (size_t)WS_AT_OFF * 2;                          // ~2.1 MB
    const size_t NEED_BIG  = ((size_t)WS_AT_OFF + (size_t)MM * 512) * 2;     // ~39.4 MB
    const size_t NEED_FULL = ((size_t)WS_AT_OFF + 4 * (size_t)MM * 512) * 2; // ~151 MB

    float* X2 = (float*)d_out;

    if (d_ws == nullptr || ws_size < NEED_W) {
        // LEGACY path (verified baseline): zero workspace bytes used.
        attn_fused<2><<<4096, 320, 0, stream>>>(query, key_, value,
                                                Wq, bq, Wk, bk, Wv, bv,
                                                w1, b1, w2, b2, X2, nullptr);
        gemm_o_inplace<1><<<284, 512, 0, stream>>>(Wo, bo, X2);
        return;
    }

    wcvt512<<<256, 256, 0, stream>>>(Wq, Wk, Wv, Wo, WqT, WkT, WvT, WoT);
    sfcvt<<<1, 256, 0, stream>>>(w1, w2, w1T, w2T);

    if (ws_size >= NEED_FULL) {
        qkv_gemm_v3<<<3408, 512, 0, stream>>>(query, key_, value,
                                              WqT, WkT, WvT, bq, bk, bv,
                                              Qp, Kp, Vp);
        attn2<<<4096, 320, 0, stream>>>(Qp, Kp, Vp, w1T, b1, w2T, b2, AT);
        gemm_o_v3<<<1136, 512, 0, stream>>>(WoT, bo, AT, X2);
    } else if (ws_size >= NEED_BIG) {
        attn_fused<1><<<4096, 320, 0, stream>>>(query, key_, value,
                                                WqT, bq, WkT, bk, WvT, bv,
                                                w1T, b1, w2T, b2, nullptr, AT);
        gemm_o_bf16_v2<<<1136, 512, 0, stream>>>(WoT, bo, AT, X2);
    } else {
        attn_fused<0><<<4096, 320, 0, stream>>>(query, key_, value,
                                                WqT, bq, WkT, bk, WvT, bv,
                                                w1T, b1, w2T, b2, X2, nullptr);
        gemm_o_inplace<0><<<284, 512, 0, stream>>>(WoT, bo, X2);
    }
}

// Round 7
// 553.888 us; speedup vs baseline: 2.1144x; 1.0137x over previous
//
#include <hip/hip_runtime.h>
#include <math.h>

#define Bb 512
#define Ll 71
#define Dd 512
#define Hh 8
#define DH 64
#define MM (Bb*Ll)   // 36352 = 284 * 128

typedef __attribute__((ext_vector_type(8))) short short8;
typedef __attribute__((ext_vector_type(4))) float f32x4;

static __device__ __forceinline__ f32x4 mfma_bf16(short8 a, short8 b, f32x4 c) {
    return __builtin_amdgcn_mfma_f32_16x16x32_bf16(a, b, c, 0, 0, 0);
}

// fp32 -> bf16 with round-to-nearest-even
static __device__ __forceinline__ unsigned short f2bf(float f) {
    union { float f; unsigned u; } v; v.f = f;
    unsigned r = v.u + 0x7FFFu + ((v.u >> 16) & 1u);
    return (unsigned short)(r >> 16);
}

// ---------------------------------------------------------------------------
// ws layout (ushort elements):
//   0        WqT  bf16 [512 n][512 k]
//   262144   WkT  bf16 [512][512]
//   524288   WvT  bf16 [512][512]
//   786432   WoT  bf16 [512][512]
//   1048576  w1T  bf16 [128 n][96 k]   (k >= 71 zeroed)
//   1060864  w2T  bf16 [80 n][128 k]   (n >= 71 rows zeroed)
//   1071104  AT   bf16 [36352][512]    (attention output)
//   19683328 Qp   bf16 [36352][512]    (projected Q, bias added)
//   38295552 Kp   bf16 [36352][512]
//   56907776 Vp   bf16 [36352][512]
// ---------------------------------------------------------------------------
#define WS_W1T_OFF 1048576
#define WS_W2T_OFF 1060864
#define WS_AT_OFF  1071104
#define WS_QP_OFF  19683328
#define WS_KP_OFF  38295552
#define WS_VP_OFF  56907776

// Transpose+convert one 64x64 tile of a 512x512 fp32 weight into bf16 [n][k].
__global__ __launch_bounds__(256) void wcvt512(
    const float* __restrict__ W0, const float* __restrict__ W1,
    const float* __restrict__ W2, const float* __restrict__ W3,
    unsigned short* __restrict__ T0, unsigned short* __restrict__ T1,
    unsigned short* __restrict__ T2, unsigned short* __restrict__ T3)
{
    __shared__ unsigned short t[64][72];
    const int m    = blockIdx.x >> 6;
    const int tile = blockIdx.x & 63;
    const float* W = (m == 0) ? W0 : (m == 1) ? W1 : (m == 2) ? W2 : W3;
    unsigned short* T = (m == 0) ? T0 : (m == 1) ? T1 : (m == 2) ? T2 : T3;
    const int tk = (tile >> 3) * 64, tn = (tile & 7) * 64;
    const int ln = threadIdx.x & 63, lr = threadIdx.x >> 6;
#pragma unroll
    for (int r = lr; r < 64; r += 4)
        t[ln][r] = f2bf(W[(size_t)(tk + r) * 512 + tn + ln]);
    __syncthreads();
#pragma unroll
    for (int r = lr; r < 64; r += 4)
        T[(size_t)(tn + r) * 512 + tk + ln] = t[r][ln];
}

// Convert w1 [71][128] -> w1T [128][96] (k>=71 zero) and
//         w2 [128][71] -> w2T [80][128] (n>=71 rows zero).
__global__ __launch_bounds__(256) void sfcvt(
    const float* __restrict__ w1, const float* __restrict__ w2,
    unsigned short* __restrict__ w1T, unsigned short* __restrict__ w2T)
{
    const int tid = threadIdx.x;
    for (int i = tid; i < 128 * 96; i += 256) {
        int n = i / 96, k = i % 96;
        w1T[i] = (k < 71) ? f2bf(w1[(size_t)k * 128 + n]) : (unsigned short)0;
    }
    for (int i = tid; i < 80 * 128; i += 256) {
        int n = i / 128, k = i % 128;
        w2T[i] = (n < 71) ? f2bf(w2[(size_t)k * 71 + n]) : (unsigned short)0;
    }
}

// ---------------------------------------------------------------------------
// QKV projection GEMM v3 (LDS-staged): 128x128 tile, BK=64, 512 thr =
// 8 waves x (32x64), double-buffered XOR-swizzled LDS, async staging.
// ---------------------------------------------------------------------------
__global__ __launch_bounds__(512) void qkv_gemm_v3(
    const float* __restrict__ X0, const float* __restrict__ X1,
    const float* __restrict__ X2i,
    const unsigned short* __restrict__ W0T,
    const unsigned short* __restrict__ W1T,
    const unsigned short* __restrict__ W2T,
    const float* __restrict__ bb0, const float* __restrict__ bb1,
    const float* __restrict__ bb2,
    unsigned short* __restrict__ O0, unsigned short* __restrict__ O1,
    unsigned short* __restrict__ O2)
{
    __shared__ unsigned short As[2][8192];   // [128][64] bf16, swizzled
    __shared__ unsigned short Bs[2][8192];

    const int tid  = threadIdx.x;
    const int wave = tid >> 6, lane = tid & 63;
    const int quad = lane >> 4, l16 = lane & 15;
    // bijective XCD swizzle: 3408 = 8 * 426
    const int g   = blockIdx.x;
    const int wg  = (g & 7) * 426 + (g >> 3);
    const int mat = wg / 1136;
    const int r_  = wg - mat * 1136;
    const int m0  = (r_ >> 2) * 128, n0 = (r_ & 3) * 128;
    const float* X = (mat == 0) ? X0 : (mat == 1) ? X1 : X2i;
    const unsigned short* WT = (mat == 0) ? W0T : (mat == 1) ? W1T : W2T;
    const float* bias = (mat == 0) ? bb0 : (mat == 1) ? bb1 : bb2;
    unsigned short* O = (mat == 0) ? O0 : (mat == 1) ? O1 : O2;

    const int wm = (wave >> 1) * 32, wn = (wave & 1) * 64;

    // staging: thread -> row sr (0..127), quarter sq (0..3) = 16 elems
    const int sr = tid >> 2, sq = tid & 3;
    const float* aglob = X + (size_t)(m0 + sr) * 512 + sq * 16;
    const unsigned short* bglob = WT + (size_t)(n0 + sr) * 512 + sq * 16;
    const int aw0 = sr * 64 + (((sq * 2 + 0) ^ (sr & 7)) << 3);
    const int aw1 = sr * 64 + (((sq * 2 + 1) ^ (sr & 7)) << 3);

    f32x4 acc[2][4];
#pragma unroll
    for (int i = 0; i < 2; i++)
#pragma unroll
        for (int j = 0; j < 4; j++) acc[i][j] = (f32x4){0.f, 0.f, 0.f, 0.f};

    // ---- prologue: stage kt=0 into buf 0
    {
        f32x4 av[4];
#pragma unroll
        for (int p = 0; p < 4; p++) av[p] = *(const f32x4*)(aglob + p * 4);
        short8 bv0 = *(const short8*)bglob;
        short8 bv1 = *(const short8*)(bglob + 8);
        short8 s0, s1;
#pragma unroll
        for (int e = 0; e < 8; e++) {
            s0[e] = (short)f2bf(av[e >> 2][e & 3]);
            s1[e] = (short)f2bf(av[2 + (e >> 2)][e & 3]);
        }
        *(short8*)&As[0][aw0] = s0;
        *(short8*)&As[0][aw1] = s1;
        *(short8*)&Bs[0][aw0] = bv0;
        *(short8*)&Bs[0][aw1] = bv1;
    }
    __syncthreads();

#pragma unroll
    for (int kt = 0; kt < 8; ++kt) {
        const int cur = kt & 1;
        f32x4 av[4];
        short8 bv0, bv1;
        if (kt < 7) {    // issue next-tile loads early (latency hides under MFMA)
            const float* ag = aglob + (kt + 1) * 64;
            const unsigned short* bg = bglob + (kt + 1) * 64;
#pragma unroll
            for (int p = 0; p < 4; p++) av[p] = *(const f32x4*)(ag + p * 4);
            bv0 = *(const short8*)bg;
            bv1 = *(const short8*)(bg + 8);
        }
        // compute current buffer
#pragma unroll
        for (int ks = 0; ks < 2; ++ks) {
            const int phys = (((ks * 4 + quad) ^ (l16 & 7)) << 3);
            short8 af[2], bf_[4];
#pragma unroll
            for (int i = 0; i < 2; i++)
                af[i] = *(const short8*)&As[cur][(wm + i * 16 + l16) * 64 + phys];
#pragma unroll
            for (int j = 0; j < 4; j++)
                bf_[j] = *(const short8*)&Bs[cur][(wn + j * 16 + l16) * 64 + phys];
#pragma unroll
            for (int i = 0; i < 2; i++)
#pragma unroll
                for (int j = 0; j < 4; j++)
                    acc[i][j] = mfma_bf16(af[i], bf_[j], acc[i][j]);
        }
        if (kt < 7) {    // convert + write next buffer
            short8 s0, s1;
#pragma unroll
            for (int e = 0; e < 8; e++) {
                s0[e] = (short)f2bf(av[e >> 2][e & 3]);
                s1[e] = (short)f2bf(av[2 + (e >> 2)][e & 3]);
            }
            const int nxt = cur ^ 1;
            *(short8*)&As[nxt][aw0] = s0;
            *(short8*)&As[nxt][aw1] = s1;
            *(short8*)&Bs[nxt][aw0] = bv0;
            *(short8*)&Bs[nxt][aw1] = bv1;
        }
        __syncthreads();
    }

#pragma unroll
    for (int j = 0; j < 4; j++) {
        const int gcol = n0 + wn + j * 16 + l16;
        const float bvf = bias[gcol];
#pragma unroll
        for (int i = 0; i < 2; i++) {
#pragma unroll
            for (int r = 0; r < 4; r++) {
                const int grow = m0 + wm + i * 16 + quad * 4 + r;
                O[(size_t)grow * 512 + gcol] = f2bf(acc[i][j][r] + bvf);
            }
        }
    }
}

// ---------------------------------------------------------------------------
// Output projection GEMM v3: same LDS-staged structure, bf16 A/B, fp32 out.
// ---------------------------------------------------------------------------
__global__ __launch_bounds__(512) void gemm_o_v3(
    const unsigned short* __restrict__ WoT,  // [512 n][512 k] bf16
    const float* __restrict__ bo,
    const unsigned short* __restrict__ AT,   // [36352][512] bf16
    float* __restrict__ Y)                   // [36352][512] fp32
{
    __shared__ unsigned short As[2][8192];
    __shared__ unsigned short Bs[2][8192];

    const int tid  = threadIdx.x;
    const int wave = tid >> 6, lane = tid & 63;
    const int quad = lane >> 4, l16 = lane & 15;
    const int g   = blockIdx.x;
    const int wg  = (g & 7) * 142 + (g >> 3);   // 1136 = 8*142
    const int m0  = (wg >> 2) * 128, n0 = (wg & 3) * 128;
    const int wm = (wave >> 1) * 32, wn = (wave & 1) * 64;

    const int sr = tid >> 2, sq = tid & 3;
    const unsigned short* aglob = AT + (size_t)(m0 + sr) * 512 + sq * 16;
    const unsigned short* bglob = WoT + (size_t)(n0 + sr) * 512 + sq * 16;
    const int aw0 = sr * 64 + (((sq * 2 + 0) ^ (sr & 7)) << 3);
    const int aw1 = sr * 64 + (((sq * 2 + 1) ^ (sr & 7)) << 3);

    f32x4 acc[2][4];
#pragma unroll
    for (int i = 0; i < 2; i++)
#pragma unroll
        for (int j = 0; j < 4; j++) acc[i][j] = (f32x4){0.f, 0.f, 0.f, 0.f};

    {
        short8 a0 = *(const short8*)aglob;
        short8 a1 = *(const short8*)(aglob + 8);
        short8 b0 = *(const short8*)bglob;
        short8 b1 = *(const short8*)(bglob + 8);
        *(short8*)&As[0][aw0] = a0;
        *(short8*)&As[0][aw1] = a1;
        *(short8*)&Bs[0][aw0] = b0;
        *(short8*)&Bs[0][aw1] = b1;
    }
    __syncthreads();

#pragma unroll
    for (int kt = 0; kt < 8; ++kt) {
        const int cur = kt & 1;
        short8 a0, a1, b0, b1;
        if (kt < 7) {
            const unsigned short* ag = aglob + (kt + 1) * 64;
            const unsigned short* bg = bglob + (kt + 1) * 64;
            a0 = *(const short8*)ag;  a1 = *(const short8*)(ag + 8);
            b0 = *(const short8*)bg;  b1 = *(const short8*)(bg + 8);
        }
#pragma unroll
        for (int ks = 0; ks < 2; ++ks) {
            const int phys = (((ks * 4 + quad) ^ (l16 & 7)) << 3);
            short8 af[2], bf_[4];
#pragma unroll
            for (int i = 0; i < 2; i++)
                af[i] = *(const short8*)&As[cur][(wm + i * 16 + l16) * 64 + phys];
#pragma unroll
            for (int j = 0; j < 4; j++)
                bf_[j] = *(const short8*)&Bs[cur][(wn + j * 16 + l16) * 64 + phys];
#pragma unroll
            for (int i = 0; i < 2; i++)
#pragma unroll
                for (int j = 0; j < 4; j++)
                    acc[i][j] = mfma_bf16(af[i], bf_[j], acc[i][j]);
        }
        if (kt < 7) {
            const int nxt = cur ^ 1;
            *(short8*)&As[nxt][aw0] = a0;
            *(short8*)&As[nxt][aw1] = a1;
            *(short8*)&Bs[nxt][aw0] = b0;
            *(short8*)&Bs[nxt][aw1] = b1;
        }
        __syncthreads();
    }

#pragma unroll
    for (int j = 0; j < 4; j++) {
        const int gcol = n0 + wn + j * 16 + l16;
        const float bvf = bo[gcol];
#pragma unroll
        for (int i = 0; i < 2; i++) {
#pragma unroll
            for (int r = 0; r < 4; r++) {
                const int grow = m0 + wm + i * 16 + quad * 4 + r;
                Y[(size_t)grow * 512 + gcol] = acc[i][j][r] + bvf;
            }
        }
    }
}

// ---------------------------------------------------------------------------
// Attention-only kernel per (b,h). 320 thr = 5 waves. ONE barrier total:
// phases 1-5 are per-wave independent (each wave reads only its own 16 rows
// of Sb/H1s); only the V-transpose scatter + zero-pads are block-wide.
// V-scatter remapped so consecutive lanes write consecutive rows (bank =
// row>>1 -> free 2-way) instead of 16-way same-bank collisions.
// ---------------------------------------------------------------------------
__global__ __launch_bounds__(320) void attn2(
    const unsigned short* __restrict__ Qp,
    const unsigned short* __restrict__ Kp,
    const unsigned short* __restrict__ Vp,
    const unsigned short* __restrict__ w1T,  // [128][96] bf16
    const float* __restrict__ b1,            // [128]
    const unsigned short* __restrict__ w2T,  // [80][128] bf16
    const float* __restrict__ b2,            // [71]
    unsigned short* __restrict__ AT)         // [36352][512] bf16
{
    __shared__ __align__(16) unsigned short smem[25856];
    unsigned short* VTs = smem;              // [64][104]  V^T, k-contig
    unsigned short* Sb  = smem + 6656;       // [80][104]
    unsigned short* H1s = smem + 14976;      // [80][136]

    const int tid = threadIdx.x;
    const int wave = tid >> 6, lane = tid & 63;
    const int quad = lane >> 4, l16 = lane & 15;
    const int x = blockIdx.x;
    const int b = ((x >> 6) << 3) | (x & 7);   // XCD-aware remap
    const int h = (x >> 3) & 7;
    const int hs = h * 64;
    const unsigned short* Qr = Qp + (size_t)(b * 71) * 512 + hs;
    const unsigned short* Kr = Kp + (size_t)(b * 71) * 512 + hs;
    const unsigned short* Vr = Vp + (size_t)(b * 71) * 512 + hs;

    // zero pads
    for (int i = tid; i < 1600; i += 320) {   // VTs k-cols [71,96) all n
        int n = i / 25, c = 71 + (i % 25);
        VTs[n * 104 + c] = 0;
    }
    for (int i = tid; i < 1280; i += 320) {   // Sb cols [80,96)
        int r = i >> 4, c = 80 + (i & 15);
        Sb[r * 104 + c] = 0;
    }
    // V scatter -> VTs[col][row]; lane t -> (c8 = t/71, row = t%71):
    // consecutive lanes hit consecutive rows -> bank = row>>1, 2-way free.
    for (int t = tid; t < 568; t += 320) {
        int c8 = t / 71, row = t - c8 * 71;
        short8 v = *(const short8*)&Vr[(size_t)row * 512 + c8 * 8];
#pragma unroll
        for (int e = 0; e < 8; e++)
            VTs[(c8 * 8 + e) * 104 + row] = (unsigned short)v[e];
    }
    __syncthreads();   // the ONLY block-wide barrier

    // ---- phase 1: scores = Q K^T / 8, Q/K frags direct from global
    f32x4 sacc[5];
#pragma unroll
    for (int t = 0; t < 5; t++) sacc[t] = (f32x4){0.f, 0.f, 0.f, 0.f};
    const int arow = wave * 16 + l16;
    const bool aok = (arow < 71);
#pragma unroll
    for (int kk = 0; kk < 2; kk++) {
        short8 aq = aok ? *(const short8*)&Qr[(size_t)arow * 512 + kk * 32 + quad * 8]
                        : (short8){0,0,0,0,0,0,0,0};
#pragma unroll
        for (int t = 0; t < 5; t++) {
            const int brow = t * 16 + l16;
            short8 bk_ = (brow < 71)
                ? *(const short8*)&Kr[(size_t)brow * 512 + kk * 32 + quad * 8]
                : (short8){0,0,0,0,0,0,0,0};
            sacc[t] = mfma_bf16(aq, bk_, sacc[t]);
        }
    }
#pragma unroll
    for (int t = 0; t < 5; t++) {
#pragma unroll
        for (int r = 0; r < 4; r++) {
            sacc[t][r] *= 0.125f;
            int row = wave * 16 + quad * 4 + r, col = t * 16 + l16;
            Sb[row * 104 + col] = f2bf(sacc[t][r]);
        }
    }
    // no barrier: phase 2 reads only this wave's own 16 rows of Sb

    // ---- phase 2: H1 = gelu(S @ W1 + b1)
    f32x4 hacc[8];
#pragma unroll
    for (int t = 0; t < 8; t++) hacc[t] = (f32x4){0.f, 0.f, 0.f, 0.f};
#pragma unroll
    for (int kk = 0; kk < 3; kk++) {
        short8 a = *(const short8*)&Sb[(wave * 16 + l16) * 104 + kk * 32 + quad * 8];
        const int k0 = kk * 32 + quad * 8;
#pragma unroll
        for (int t = 0; t < 8; t++) {
            short8 bw = *(const short8*)&w1T[(size_t)(t * 16 + l16) * 96 + k0];
            hacc[t] = mfma_bf16(a, bw, hacc[t]);
        }
    }
#pragma unroll
    for (int t = 0; t < 8; t++) {
        int col = t * 16 + l16;
        float bvf = b1[col];
#pragma unroll
        for (int r = 0; r < 4; r++) {
            float z = hacc[t][r] + bvf;
            float g = 0.5f * z * (1.0f + erff(z * 0.70710678118654752f));
            int row = wave * 16 + quad * 4 + r;
            H1s[row * 136 + col] = f2bf(g);
        }
    }
    // no barrier: phase 3 reads only this wave's own 16 rows of H1s

    // ---- phase 3: G = H1 @ W2
    f32x4 gacc[5];
#pragma unroll
    for (int t = 0; t < 5; t++) gacc[t] = (f32x4){0.f, 0.f, 0.f, 0.f};
#pragma unroll
    for (int kk = 0; kk < 4; kk++) {
        short8 a = *(const short8*)&H1s[(wave * 16 + l16) * 136 + kk * 32 + quad * 8];
        const int k0 = kk * 32 + quad * 8;
#pragma unroll
        for (int t = 0; t < 5; t++) {
            short8 bw = *(const short8*)&w2T[(size_t)(t * 16 + l16) * 128 + k0];
            gacc[t] = mfma_bf16(a, bw, gacc[t]);
        }
    }
#pragma unroll
    for (int t = 0; t < 5; t++) {
        int col = t * 16 + l16;
        float b2v = (col < 71) ? b2[col] : 0.f;
#pragma unroll
        for (int r = 0; r < 4; r++)
            sacc[t][r] = sacc[t][r] + gacc[t][r] + b2v;
    }

    // ---- phase 4: softmax over cols 0..70
    bool valid4 = (l16 < 7);
#pragma unroll
    for (int r = 0; r < 4; r++) {
        float mx = -1e30f;
#pragma unroll
        for (int t = 0; t < 5; t++) {
            float v = sacc[t][r];
            if (t == 4 && !valid4) v = -1e30f;
            mx = fmaxf(mx, v);
        }
#pragma unroll
        for (int off = 1; off < 16; off <<= 1) mx = fmaxf(mx, __shfl_xor(mx, off, 16));
        float sum = 0.f;
#pragma unroll
        for (int t = 0; t < 5; t++) {
            float e = (t == 4 && !valid4) ? 0.f : __expf(sacc[t][r] - mx);
            sacc[t][r] = e;
            sum += e;
        }
#pragma unroll
        for (int off = 1; off < 16; off <<= 1) sum += __shfl_xor(sum, off, 16);
        float inv = 1.0f / sum;
#pragma unroll
        for (int t = 0; t < 5; t++) sacc[t][r] *= inv;
    }
#pragma unroll
    for (int t = 0; t < 5; t++) {
#pragma unroll
        for (int r = 0; r < 4; r++) {
            int row = wave * 16 + quad * 4 + r, col = t * 16 + l16;
            Sb[row * 104 + col] = f2bf(sacc[t][r]);   // P; cols 71..95 exact 0
        }
    }
    // no barrier: phase 5 reads only this wave's own 16 rows of Sb (P)

    // ---- phase 5: O = P @ V -> AT bf16
    f32x4 oacc[4];
#pragma unroll
    for (int t = 0; t < 4; t++) oacc[t] = (f32x4){0.f, 0.f, 0.f, 0.f};
#pragma unroll
    for (int kk = 0; kk < 3; kk++) {
        short8 a = *(const short8*)&Sb[(wave * 16 + l16) * 104 + kk * 32 + quad * 8];
#pragma unroll
        for (int t = 0; t < 4; t++) {
            short8 bvv = *(const short8*)&VTs[(t * 16 + l16) * 104 + kk * 32 + quad * 8];
            oacc[t] = mfma_bf16(a, bvv, oacc[t]);
        }
    }
#pragma unroll
    for (int r = 0; r < 4; r++) {
        int l = wave * 16 + quad * 4 + r;
        if (l < 71) {
#pragma unroll
            for (int t = 0; t < 4; t++)
                AT[(size_t)(b * 71 + l) * 512 + hs + t * 16 + l16] = f2bf(oacc[t][r]);
        }
    }
}

// ---------------------------------------------------------------------------
// Fallback projection helpers + fused kernel (verified paths).
// ---------------------------------------------------------------------------
static __device__ __forceinline__ void proj_g(
    const float* __restrict__ Xrows,
    const unsigned short* __restrict__ WT,
    int hs, int wave, int quad, int l16, f32x4 acc[4])
{
    const int arow = wave * 16 + l16;
    const bool ok = (arow < 71);
    const float* ap = Xrows + (size_t)arow * 512 + quad * 8;
    const unsigned short* w0 = WT + (size_t)(hs + l16) * 512 + quad * 8;
#pragma unroll 4
    for (int kk = 0; kk < 16; ++kk) {
        short8 a;
        if (ok) {
            const f32x4 p0 = *(const f32x4*)(ap + (size_t)kk * 32);
            const f32x4 p1 = *(const f32x4*)(ap + (size_t)kk * 32 + 4);
#pragma unroll
            for (int j = 0; j < 4; j++) {
                a[j]     = (short)f2bf(p0[j]);
                a[4 + j] = (short)f2bf(p1[j]);
            }
        } else {
            a = (short8){0,0,0,0,0,0,0,0};
        }
#pragma unroll
        for (int t = 0; t < 4; t++) {
            short8 bw = *(const short8*)(w0 + (size_t)t * (16 * 512) + kk * 32);
            acc[t] = mfma_bf16(a, bw, acc[t]);
        }
    }
}

static __device__ __forceinline__ void proj_g_legacy(
    const float* __restrict__ Xrows,
    const float* __restrict__ W,
    int hs, int wave, int quad, int l16, f32x4 acc[4])
{
    const int arow = wave * 16 + l16;
    const bool ok = (arow < 71);
    const float* ap = Xrows + (size_t)arow * 512 + quad * 8;
    const int nb = hs + l16;
#pragma unroll 2
    for (int kk = 0; kk < 16; ++kk) {
        short8 a;
        if (ok) {
            const float* p = ap + (size_t)kk * 32;
#pragma unroll
            for (int j = 0; j < 8; j++) a[j] = (short)f2bf(p[j]);
        } else {
            a = (short8){0,0,0,0,0,0,0,0};
        }
        const int k0 = kk * 32 + quad * 8;
#pragma unroll
        for (int t = 0; t < 4; t++) {
            const float* wp = W + (size_t)k0 * 512 + nb + t * 16;
            short8 bw;
#pragma unroll
            for (int j = 0; j < 8; j++) bw[j] = (short)f2bf(wp[(size_t)j * 512]);
            acc[t] = mfma_bf16(a, bw, acc[t]);
        }
    }
}

// MODE 0: bf16 W, fp32 X, fp32 out.  MODE 1: bf16 W, fp32 X, bf16 out.
// MODE 2: legacy fp32 everything.
template<int MODE>
__global__ __launch_bounds__(320) void attn_fused(
    const float* __restrict__ query,
    const float* __restrict__ key_,
    const float* __restrict__ value,
    const void* __restrict__ Wq_, const float* __restrict__ bq,
    const void* __restrict__ Wk_, const float* __restrict__ bk,
    const void* __restrict__ Wv_, const float* __restrict__ bv,
    const void* __restrict__ w1_,
    const float* __restrict__ b1,
    const void* __restrict__ w2_,
    const float* __restrict__ b2,
    float* __restrict__ X2,
    unsigned short* __restrict__ AT)
{
    __shared__ __align__(16) unsigned short smem[26496];
    unsigned short* Qs  = smem;              // [80][72]
    unsigned short* Ks  = smem + 5760;       // [80][72]
    unsigned short* H1s = smem;              // [80][136] overlays Qs+Ks
    unsigned short* VTs = smem + 11520;      // [64][104]
    unsigned short* Sb  = smem + 18176;      // [80][104]

    const int tid = threadIdx.x;
    const int wave = tid >> 6, lane = tid & 63;
    const int quad = lane >> 4, l16 = lane & 15;
    const int x = blockIdx.x;
    const int b = ((x >> 6) << 3) | (x & 7);
    const int h = (x >> 3) & 7;
    const int hs = h * 64;
    const float* Xq = query + (size_t)(b * 71) * 512;
    const float* Xk = key_  + (size_t)(b * 71) * 512;
    const float* Xv = value + (size_t)(b * 71) * 512;

    for (int i = tid; i < 1280; i += 320) {
        int r = i >> 4, c = 80 + (i & 15);
        Sb[r * 104 + c] = 0;
    }
    for (int i = tid; i < 1024; i += 320) {
        int n = i >> 4, c = 80 + (i & 15);
        VTs[n * 104 + c] = 0;
    }

    {
        f32x4 acc[4];
#pragma unroll
        for (int t = 0; t < 4; t++) acc[t] = (f32x4){0.f, 0.f, 0.f, 0.f};
        if (MODE == 2) proj_g_legacy(Xq, (const float*)Wq_, hs, wave, quad, l16, acc);
        else           proj_g(Xq, (const unsigned short*)Wq_, hs, wave, quad, l16, acc);
#pragma unroll
        for (int t = 0; t < 4; t++) {
            int col = t * 16 + l16;
            float bb = bq[hs + col];
#pragma unroll
            for (int r = 0; r < 4; r++) {
                int row = wave * 16 + quad * 4 + r;
                Qs[row * 72 + col] = f2bf(acc[t][r] + bb);
            }
        }
    }
    {
        f32x4 acc[4];
#pragma unroll
        for (int t = 0; t < 4; t++) acc[t] = (f32x4){0.f, 0.f, 0.f, 0.f};
        if (MODE == 2) proj_g_legacy(Xk, (const float*)Wk_, hs, wave, quad, l16, acc);
        else           proj_g(Xk, (const unsigned short*)Wk_, hs, wave, quad, l16, acc);
#pragma unroll
        for (int t = 0; t < 4; t++) {
            int col = t * 16 + l16;
            float bb = bk[hs + col];
#pragma unroll
            for (int r = 0; r < 4; r++) {
                int row = wave * 16 + quad * 4 + r;
                Ks[row * 72 + col] = f2bf(acc[t][r] + bb);
            }
        }
    }
    {
        f32x4 acc[4];
#pragma unroll
        for (int t = 0; t < 4; t++) acc[t] = (f32x4){0.f, 0.f, 0.f, 0.f};
        if (MODE == 2) proj_g_legacy(Xv, (const float*)Wv_, hs, wave, quad, l16, acc);
        else           proj_g(Xv, (const unsigned short*)Wv_, hs, wave, quad, l16, acc);
#pragma unroll
        for (int t = 0; t < 4; t++) {
            int col = t * 16 + l16;
            float bb = bv[hs + col];
#pragma unroll
            for (int r = 0; r < 4; r++) {
                int row = wave * 16 + quad * 4 + r;
                float v = (row < 71) ? (acc[t][r] + bb) : 0.f;
                VTs[col * 104 + row] = f2bf(v);
            }
        }
    }
    __syncthreads();

    f32x4 sacc[5];
#pragma unroll
    for (int t = 0; t < 5; t++) sacc[t] = (f32x4){0.f, 0.f, 0.f, 0.f};
#pragma unroll
    for (int kk = 0; kk < 2; kk++) {
        short8 aq = *(const short8*)&Qs[(wave * 16 + l16) * 72 + kk * 32 + quad * 8];
#pragma unroll
        for (int t = 0; t < 5; t++) {
            short8 bk_ = *(const short8*)&Ks[(t * 16 + l16) * 72 + kk * 32 + quad * 8];
            sacc[t] = mfma_bf16(aq, bk_, sacc[t]);
        }
    }
#pragma unroll
    for (int t = 0; t < 5; t++) {
#pragma unroll
        for (int r = 0; r < 4; r++) {
            sacc[t][r] *= 0.125f;
            int row = wave * 16 + quad * 4 + r, col = t * 16 + l16;
            Sb[row * 104 + col] = f2bf(sacc[t][r]);
        }
    }
    __syncthreads();

    f32x4 hacc[8];
#pragma unroll
    for (int t = 0; t < 8; t++) hacc[t] = (f32x4){0.f, 0.f, 0.f, 0.f};
#pragma unroll
    for (int kk = 0; kk < 3; kk++) {
        short8 a = *(const short8*)&Sb[(wave * 16 + l16) * 104 + kk * 32 + quad * 8];
        const int k0 = kk * 32 + quad * 8;
#pragma unroll
        for (int t = 0; t < 8; t++) {
            short8 bw;
            if (MODE == 2) {
                const float* wp = (const float*)w1_ + (size_t)k0 * 128 + t * 16 + l16;
#pragma unroll
                for (int j = 0; j < 8; j++)
                    bw[j] = (k0 + j < 71) ? (short)f2bf(wp[(size_t)j * 128]) : (short)0;
            } else {
                bw = *(const short8*)&((const unsigned short*)w1_)[(size_t)(t * 16 + l16) * 96 + k0];
            }
            hacc[t] = mfma_bf16(a, bw, hacc[t]);
        }
    }
#pragma unroll
    for (int t = 0; t < 8; t++) {
        int col = t * 16 + l16;
        float bvf = b1[col];
#pragma unroll
        for (int r = 0; r < 4; r++) {
            float z = hacc[t][r] + bvf;
            float g = 0.5f * z * (1.0f + erff(z * 0.70710678118654752f));
            int row = wave * 16 + quad * 4 + r;
            H1s[row * 136 + col] = f2bf(g);
        }
    }
    __syncthreads();

    f32x4 gacc[5];
#pragma unroll
    for (int t = 0; t < 5; t++) gacc[t] = (f32x4){0.f, 0.f, 0.f, 0.f};
#pragma unroll
    for (int kk = 0; kk < 4; kk++) {
        short8 a = *(const short8*)&H1s[(wave * 16 + l16) * 136 + kk * 32 + quad * 8];
        const int k0 = kk * 32 + quad * 8;
#pragma unroll
        for (int t = 0; t < 5; t++) {
            short8 bw;
            if (MODE == 2) {
                const int n = t * 16 + l16;
                const float* wp = (const float*)w2_ + (size_t)k0 * 71 + n;
#pragma unroll
                for (int j = 0; j < 8; j++)
                    bw[j] = (n < 71) ? (short)f2bf(wp[(size_t)j * 71]) : (short)0;
            } else {
                bw = *(const short8*)&((const unsigned short*)w2_)[(size_t)(t * 16 + l16) * 128 + k0];
            }
            gacc[t] = mfma_bf16(a, bw, gacc[t]);
        }
    }
#pragma unroll
    for (int t = 0; t < 5; t++) {
        int col = t * 16 + l16;
        float b2v = (col < 71) ? b2[col] : 0.f;
#pragma unroll
        for (int r = 0; r < 4; r++)
            sacc[t][r] = sacc[t][r] + gacc[t][r] + b2v;
    }

    bool valid4 = (l16 < 7);
#pragma unroll
    for (int r = 0; r < 4; r++) {
        float mx = -1e30f;
#pragma unroll
        for (int t = 0; t < 5; t++) {
            float v = sacc[t][r];
            if (t == 4 && !valid4) v = -1e30f;
            mx = fmaxf(mx, v);
        }
#pragma unroll
        for (int off = 1; off < 16; off <<= 1) mx = fmaxf(mx, __shfl_xor(mx, off, 16));
        float sum = 0.f;
#pragma unroll
        for (int t = 0; t < 5; t++) {
            float e = (t == 4 && !valid4) ? 0.f : __expf(sacc[t][r] - mx);
            sacc[t][r] = e;
            sum += e;
        }
#pragma unroll
        for (int off = 1; off < 16; off <<= 1) sum += __shfl_xor(sum, off, 16);
        float inv = 1.0f / sum;
#pragma unroll
        for (int t = 0; t < 5; t++) sacc[t][r] *= inv;
    }
#pragma unroll
    for (int t = 0; t < 5; t++) {
#pragma unroll
        for (int r = 0; r < 4; r++) {
            int row = wave * 16 + quad * 4 + r, col = t * 16 + l16;
            Sb[row * 104 + col] = f2bf(sacc[t][r]);
        }
    }
    __syncthreads();

    f32x4 oacc[4];
#pragma unroll
    for (int t = 0; t < 4; t++) oacc[t] = (f32x4){0.f, 0.f, 0.f, 0.f};
#pragma unroll
    for (int kk = 0; kk < 3; kk++) {
        short8 a = *(const short8*)&Sb[(wave * 16 + l16) * 104 + kk * 32 + quad * 8];
#pragma unroll
        for (int t = 0; t < 4; t++) {
            short8 bvv = *(const short8*)&VTs[(t * 16 + l16) * 104 + kk * 32 + quad * 8];
            oacc[t] = mfma_bf16(a, bvv, oacc[t]);
        }
    }
#pragma unroll
    for (int r = 0; r < 4; r++) {
        int l = wave * 16 + quad * 4 + r;
        if (l < 71) {
#pragma unroll
            for (int t = 0; t < 4; t++) {
                int col = hs + t * 16 + l16;
                if (MODE == 1)
                    AT[(size_t)(b * 71 + l) * 512 + col] = f2bf(oacc[t][r]);
                else
                    X2[(size_t)(b * 71 + l) * 512 + col] = oacc[t][r];
            }
        }
    }
}

// Fallback O-projection (NEED_BIG path): register double-buffer version.
__global__ __launch_bounds__(512) void gemm_o_bf16_v2(
    const unsigned short* __restrict__ WoT,
    const float* __restrict__ bo,
    const unsigned short* __restrict__ AT,
    float* __restrict__ Y)
{
    const int tid  = threadIdx.x;
    const int wave = tid >> 6, lane = tid & 63;
    const int quad = lane >> 4, l16 = lane & 15;
    const int g   = blockIdx.x;
    const int wg  = (g & 7) * 142 + (g >> 3);
    const int m0  = (wg >> 2) * 128;
    const int n0  = (wg & 3) * 128;
    const int wm  = (wave >> 1) * 32, wn = (wave & 1) * 64;

    f32x4 acc[2][4];
#pragma unroll
    for (int i = 0; i < 2; i++)
#pragma unroll
        for (int j = 0; j < 4; j++) acc[i][j] = (f32x4){0.f, 0.f, 0.f, 0.f};

#define LDA(kk,i) (*(const short8*)&AT[(size_t)(m0 + wm + (i) * 16 + l16) * 512 + (kk) * 32 + quad * 8])
#define LDB(kk,j) (*(const short8*)&WoT[(size_t)(n0 + wn + (j) * 16 + l16) * 512 + (kk) * 32 + quad * 8])

    short8 aE[2], bE[4], aO[2], bO[4];
#pragma unroll
    for (int i = 0; i < 2; i++) aE[i] = LDA(0, i);
#pragma unroll
    for (int j = 0; j < 4; j++) bE[j] = LDB(0, j);

#pragma unroll
    for (int kp = 0; kp < 8; ++kp) {
        const int ko = 2 * kp + 1;
#pragma unroll
        for (int i = 0; i < 2; i++) aO[i] = LDA(ko, i);
#pragma unroll
        for (int j = 0; j < 4; j++) bO[j] = LDB(ko, j);
#pragma unroll
        for (int i = 0; i < 2; i++)
#pragma unroll
            for (int j = 0; j < 4; j++)
                acc[i][j] = mfma_bf16(aE[i], bE[j], acc[i][j]);
        if (kp < 7) {
            const int ke = 2 * kp + 2;
#pragma unroll
            for (int i = 0; i < 2; i++) aE[i] = LDA(ke, i);
#pragma unroll
            for (int j = 0; j < 4; j++) bE[j] = LDB(ke, j);
        }
#pragma unroll
        for (int i = 0; i < 2; i++)
#pragma unroll
            for (int j = 0; j < 4; j++)
                acc[i][j] = mfma_bf16(aO[i], bO[j], acc[i][j]);
    }
#undef LDA
#undef LDB

#pragma unroll
    for (int j = 0; j < 4; j++) {
        int gcol = n0 + wn + j * 16 + l16;
        float bvf = bo[gcol];
#pragma unroll
        for (int i = 0; i < 2; i++) {
#pragma unroll
            for (int r = 0; r < 4; r++) {
                int grow = m0 + wm + i * 16 + quad * 4 + r;
                Y[(size_t)grow * 512 + gcol] = acc[i][j][r] + bvf;
            }
        }
    }
}

// Fallback in-place O-projection. WMODE 0: bf16 WoT. WMODE 1: fp32 Wo gather.
template<int WMODE>
__global__ __launch_bounds__(512, 2) void gemm_o_inplace(
    const void* __restrict__ Wo_,
    const float* __restrict__ bo,
    float* __restrict__ Y)
{
    const int tid  = threadIdx.x;
    const int wave = tid >> 6, lane = tid & 63;
    const int quad = lane >> 4, l16 = lane & 15;
    const int m0 = blockIdx.x * 128;
    const int wm = (wave >> 2) * 64, wn = (wave & 3) * 128;

    f32x4 acc[4][8];
#pragma unroll
    for (int i = 0; i < 4; i++)
#pragma unroll
        for (int j = 0; j < 8; j++) acc[i][j] = (f32x4){0.f, 0.f, 0.f, 0.f};

    for (int kk = 0; kk < 16; ++kk) {
        const int k0 = kk * 32 + quad * 8;
        short8 af[4];
#pragma unroll
        for (int i = 0; i < 4; i++) {
            const float* p = Y + (size_t)(m0 + wm + i * 16 + l16) * 512 + k0;
            short8 a;
#pragma unroll
            for (int j = 0; j < 8; j++) a[j] = (short)f2bf(p[j]);
            af[i] = a;
        }
        short8 bfr[8];
#pragma unroll
        for (int j = 0; j < 8; j++) {
            if (WMODE == 1) {
                const float* wp = (const float*)Wo_ + (size_t)k0 * 512 + wn + j * 16 + l16;
                short8 bw;
#pragma unroll
                for (int e = 0; e < 8; e++) bw[e] = (short)f2bf(wp[(size_t)e * 512]);
                bfr[j] = bw;
            } else {
                bfr[j] = *(const short8*)&((const unsigned short*)Wo_)[(size_t)(wn + j * 16 + l16) * 512 + k0];
            }
        }
#pragma unroll
        for (int i = 0; i < 4; i++)
#pragma unroll
            for (int j = 0; j < 8; j++)
                acc[i][j] = mfma_bf16(af[i], bfr[j], acc[i][j]);
    }

    __syncthreads();

#pragma unroll
    for (int j = 0; j < 8; j++) {
        int gcol = wn + j * 16 + l16;
        float bvf = bo[gcol];
#pragma unroll
        for (int i = 0; i < 4; i++) {
#pragma unroll
            for (int r = 0; r < 4; r++) {
                int grow = m0 + wm + i * 16 + quad * 4 + r;
                Y[(size_t)grow * 512 + gcol] = acc[i][j][r] + bvf;
            }
        }
    }
}

extern "C" void kernel_launch(void* const* d_in, const int* in_sizes, int n_in,
                              void* d_out, int out_size, void* d_ws, size_t ws_size,
                              hipStream_t stream) {
    (void)in_sizes; (void)n_in; (void)out_size;
    const float* query = (const float*)d_in[0];
    const float* key_  = (const float*)d_in[1];
    const float* value = (const float*)d_in[2];
    const float* Wq = (const float*)d_in[3];
    const float* bq = (const float*)d_in[4];
    const float* Wk = (const float*)d_in[5];
    const float* bk = (const float*)d_in[6];
    const float* Wv = (const float*)d_in[7];
    const float* bv = (const float*)d_in[8];
    const float* Wo = (const float*)d_in[9];
    const float* bo = (const float*)d_in[10];
    const float* w1 = (const float*)d_in[11];
    const float* b1 = (const float*)d_in[12];
    const float* w2 = (const float*)d_in[13];
    const float* b2 = (const float*)d_in[14];

    unsigned short* wsT = (unsigned short*)d_ws;
    unsigned short* WqT = wsT;
    unsigned short* WkT = wsT + 262144;
    unsigned short* WvT = wsT + 524288;
    unsigned short* WoT = wsT + 786432;
    unsigned short* w1T = wsT + WS_W1T_OFF;
    unsigned short* w2T = wsT + WS_W2T_OFF;
    unsigned short* AT  = wsT + WS_AT_OFF;
    unsigned short* Qp  = wsT + WS_QP_OFF;
    unsigned short* Kp  = wsT + WS_KP_OFF;
    unsigned short* Vp  = wsT + WS_VP_OFF;
    const size_t NEED_W    = (size_t)WS_AT_OFF * 2;                          // ~2.1 MB
    const size_t NEED_BIG  = ((size_t)WS_AT_OFF + (size_t)MM * 512) * 2;     // ~39.4 MB
    const size_t NEED_FULL = ((size_t)WS_AT_OFF + 4 * (size_t)MM * 512) * 2; // ~151 MB

    float* X2 = (float*)d_out;

    if (d_ws == nullptr || ws_size < NEED_W) {
        // LEGACY path (verified baseline): zero workspace bytes used.
        attn_fused<2><<<4096, 320, 0, stream>>>(query, key_, value,
                                                Wq, bq, Wk, bk, Wv, bv,
                                                w1, b1, w2, b2, X2, nullptr);
        gemm_o_inplace<1><<<284, 512, 0, stream>>>(Wo, bo, X2);
        return;
    }

    wcvt512<<<256, 256, 0, stream>>>(Wq, Wk, Wv, Wo, WqT, WkT, WvT, WoT);
    sfcvt<<<1, 256, 0, stream>>>(w1, w2, w1T, w2T);

    if (ws_size >= NEED_FULL) {
        qkv_gemm_v3<<<3408, 512, 0, stream>>>(query, key_, value,
                                              WqT, WkT, WvT, bq, bk, bv,
                                              Qp, Kp, Vp);
        attn2<<<4096, 320, 0, stream>>>(Qp, Kp, Vp, w1T, b1, w2T, b2, AT);
        gemm_o_v3<<<1136, 512, 0, stream>>>(WoT, bo, AT, X2);
    } else if (ws_size >= NEED_BIG) {
        attn_fused<1><<<4096, 320, 0, stream>>>(query, key_, value,
                                                WqT, bq, WkT, bk, WvT, bv,
                                                w1T, b1, w2T, b2, nullptr, AT);
        gemm_o_bf16_v2<<<1136, 512, 0, stream>>>(WoT, bo, AT, X2);
    } else {
        attn_fused<0><<<4096, 320, 0, stream>>>(query, key_, value,
                                                WqT, bq, WkT, bk, WvT, bv,
                                                w1T, b1, w2T, b2, X2, nullptr);
        gemm_o_inplace<0><<<284, 512, 0, stream>>>(WoT, bo, X2);
    }
}